// Round 13
// baseline (523.118 us; speedup 1.0000x reference)
//
#include <hip/hip_runtime.h>
#include <hip/hip_fp8.h>

#define N_NODES   50000
#define N_EDGES   1600000
#define N_GRAPHS  512
#define IN_SIZE   44
#define HIDDEN    256
#define CONV_NUMS 3
#define NBK       ((N_NODES + 255) / 256)   // 196 dst-buckets of 256 nodes
#define XK        48                        // bf16 X row stride (self-term)
#define XK8       64                        // fp8 X row stride (gather table, padded)
#define PLANE_U   ((size_t)N_NODES * 16)    // uints per 64-col fp8 plane

typedef __attribute__((ext_vector_type(8))) short short8v;   // 8 bf16 = 16 B
typedef __attribute__((ext_vector_type(4))) float f32x4;     // MFMA C/D frag
typedef __attribute__((ext_vector_type(2))) float f32x2;

__device__ __forceinline__ float bf2f(unsigned short u) {
    return __uint_as_float(((unsigned int)u) << 16);
}
__device__ __forceinline__ unsigned short f2bf(float f) {
    unsigned int u = __float_as_uint(f);
    unsigned int r = (u + 0x7fffu + ((u >> 16) & 1u)) >> 16;  // RNE
    return (unsigned short)r;
}

// ---- fp8 e4m3 (OCP on gfx950) helpers: HW cvt with HIP-type fallback ----
#if __has_builtin(__builtin_amdgcn_cvt_f32_fp8)
template <int SEL>
__device__ __forceinline__ float fp8tof(unsigned int w) {
    return __builtin_amdgcn_cvt_f32_fp8((int)w, SEL);
}
#else
template <int SEL>
__device__ __forceinline__ float fp8tof(unsigned int w) {
    __hip_fp8_e4m3 q;
    q.__x = (__hip_fp8_storage_t)((w >> (SEL * 8)) & 0xff);
    return (float)q;
}
#endif

#if __has_builtin(__builtin_amdgcn_cvt_pk_f32_fp8)
template <int HI>
__device__ __forceinline__ f32x2 pk2f(unsigned int w) {
    return __builtin_amdgcn_cvt_pk_f32_fp8((int)w, HI != 0);
}
#else
template <int HI>
__device__ __forceinline__ f32x2 pk2f(unsigned int w) {
    f32x2 r;
    r.x = fp8tof<2 * HI>(w);
    r.y = fp8tof<2 * HI + 1>(w);
    return r;
}
#endif

#if __has_builtin(__builtin_amdgcn_cvt_pk_fp8_f32)
__device__ __forceinline__ unsigned int pk4fp8(float f0, float f1, float f2, float f3) {
    int lo = __builtin_amdgcn_cvt_pk_fp8_f32(f0, f1, 0, false);
    return (unsigned int)__builtin_amdgcn_cvt_pk_fp8_f32(f2, f3, lo, true);
}
#else
__device__ __forceinline__ unsigned int pk4fp8(float f0, float f1, float f2, float f3) {
    __hip_fp8_e4m3 a(f0), b(f1), c(f2), d(f3);
    return (unsigned int)a.__x | ((unsigned int)b.__x << 8) |
           ((unsigned int)c.__x << 16) | ((unsigned int)d.__x << 24);
}
#endif

__device__ __forceinline__ unsigned char f2fp8(float f) {
    return (unsigned char)(pk4fp8(f, 0.f, 0.f, 0.f) & 0xff);
}

// ========== fused: bucket/graph histograms + weight pack + X cast ===========
__global__ __launch_bounds__(256) void k_build0(const int* __restrict__ dst,
                                                const int* __restrict__ gid,
                                                const float* __restrict__ Wl,
                                                const float* __restrict__ Wproj,
                                                const float* __restrict__ X,
                                                int* __restrict__ bucket_cnt,
                                                int* __restrict__ gcnt,
                                                unsigned short* __restrict__ WlPack,
                                                unsigned short* __restrict__ WprojPack,
                                                unsigned short* __restrict__ Xb,
                                                unsigned char* __restrict__ Xb8p) {
    int b = blockIdx.x;
    int tid = threadIdx.x;
    if (b < 512) {
        __shared__ int hb[NBK];
        __shared__ int hg[N_GRAPHS];
        for (int i = tid; i < NBK; i += 256) hb[i] = 0;
        for (int i = tid; i < N_GRAPHS; i += 256) hg[i] = 0;
        __syncthreads();
        int t = b * 256 + tid;
        int stride = 512 * 256;
        for (int e = t; e < N_EDGES; e += stride) atomicAdd(&hb[dst[e] >> 8], 1);
        for (int v = t; v < N_NODES; v += stride) atomicAdd(&hg[gid[v]], 1);
        __syncthreads();
        for (int i = tid; i < NBK; i += 256) if (hb[i]) atomicAdd(&bucket_cnt[i], hb[i]);
        for (int i = tid; i < N_GRAPHS; i += 256) if (hg[i]) atomicAdd(&gcnt[i], hg[i]);
    } else if (b < 544) {               // WlPack: 8192 frags
        int i = (b - 512) * 256 + tid;
        int kg = i >> 8, n = i & 255;
        short8v v;
#pragma unroll
        for (int j = 0; j < 8; j++) v[j] = (short)f2bf(Wl[(kg * 8 + j) * HIDDEN + n]);
        *(short8v*)(WlPack + (size_t)(kg * 256 + n) * 8) = v;
    } else if (b < 552) {               // WprojPack: kg in [0,8), zero-pad k>=44
        int i = (b - 544) * 256 + tid;
        int kg = i >> 8, n = i & 255;
        short8v v;
#pragma unroll
        for (int j = 0; j < 8; j++) {
            int k = kg * 8 + j;
            v[j] = (k < IN_SIZE) ? (short)f2bf(Wproj[k * HIDDEN + n]) : (short)0;
        }
        *(short8v*)(WprojPack + (size_t)(kg * 256 + n) * 8) = v;
    } else {                            // Xb8p: N x 64 fp8 (+ Xb: N x 48 bf16)
        const int TOT8 = N_NODES * XK8;
        int id0 = (b - 552) * 2048 + tid;
#pragma unroll
        for (int j = 0; j < 8; j++) {
            int id = id0 + j * 256;
            if (id < TOT8) {
                int row = id >> 6, c = id & 63;
                float val = (c < IN_SIZE) ? X[row * IN_SIZE + c] : 0.f;
                Xb8p[id] = f2fp8(val);
                if (c < XK) Xb[(size_t)row * XK + c] = f2bf(val);
            }
        }
    }
}

__global__ void k_bscan(const int* __restrict__ bucket_cnt, int* __restrict__ bucket_base,
                        int* __restrict__ bucket_cursor, int* __restrict__ row_ptr) {
    __shared__ int s[256];
    int t = threadIdx.x;
    int v = (t < NBK) ? bucket_cnt[t] : 0;
    s[t] = v;
    __syncthreads();
    for (int off = 1; off < 256; off <<= 1) {
        int a = (t >= off) ? s[t - off] : 0;
        __syncthreads();
        s[t] += a;
        __syncthreads();
    }
    if (t < NBK) {
        int base = s[t] - v;
        bucket_base[t] = base;
        bucket_cursor[t] = base;
    }
    if (t == 0) {
        bucket_base[NBK] = N_EDGES;
        row_ptr[N_NODES] = N_EDGES;
    }
}

#define BCH 8192
__global__ __launch_bounds__(256) void k_passB(const int* __restrict__ src,
                                               const int* __restrict__ dst,
                                               int* __restrict__ bucket_cursor,
                                               int* __restrict__ pairs) {
    __shared__ int hist[NBK];
    __shared__ int excl[NBK];
    __shared__ int cur[NBK];
    __shared__ int gbase[NBK];
    __shared__ int lp[BCH];
    __shared__ int sc[256];
    int tid = threadIdx.x;
    int e0 = blockIdx.x * BCH;
    int cnt = min(BCH, N_EDGES - e0);
    for (int i = tid; i < NBK; i += 256) hist[i] = 0;
    __syncthreads();
    for (int i = tid; i < cnt; i += 256) atomicAdd(&hist[dst[e0 + i] >> 8], 1);
    __syncthreads();
    int hv = (tid < NBK) ? hist[tid] : 0;
    sc[tid] = hv;
    __syncthreads();
    for (int off = 1; off < 256; off <<= 1) {
        int a = (tid >= off) ? sc[tid - off] : 0;
        __syncthreads();
        sc[tid] += a;
        __syncthreads();
    }
    if (tid < NBK) {
        excl[tid] = sc[tid] - hv;
        cur[tid]  = sc[tid] - hv;
    }
    __syncthreads();
    for (int i = tid; i < cnt; i += 256) {
        int d = dst[e0 + i];
        int b = d >> 8;
        int pos = atomicAdd(&cur[b], 1);
        lp[pos] = (b << 24) | ((d & 255) << 16) | src[e0 + i];
    }
    __syncthreads();
    if (tid < NBK && hist[tid] > 0)
        gbase[tid] = atomicAdd(&bucket_cursor[tid], hist[tid]);
    __syncthreads();
    for (int i = tid; i < cnt; i += 256) {
        int p = lp[i];
        int b = (p >> 24) & 0xff;
        pairs[gbase[b] + (i - excl[b])] = p;
    }
}

__global__ __launch_bounds__(256) void k_passC(const int* __restrict__ pairs,
                                               const int* __restrict__ bucket_base,
                                               int* __restrict__ row_ptr,
                                               unsigned short* __restrict__ colu) {
    __shared__ int hist[256];
    __shared__ int cur[256];
    __shared__ int sc[256];
    int b = blockIdx.x;
    int tid = threadIdx.x;
    int v0 = b << 8;
    int e0 = bucket_base[b], e1 = bucket_base[b + 1];
    hist[tid] = 0;
    __syncthreads();
    for (int i = e0 + tid; i < e1; i += 256) atomicAdd(&hist[(pairs[i] >> 16) & 0xff], 1);
    __syncthreads();
    int hv = hist[tid];
    sc[tid] = hv;
    __syncthreads();
    for (int off = 1; off < 256; off <<= 1) {
        int a = (tid >= off) ? sc[tid - off] : 0;
        __syncthreads();
        sc[tid] += a;
        __syncthreads();
    }
    int base = e0 + sc[tid] - hv;
    int v = v0 + tid;
    if (v < N_NODES) row_ptr[v] = base;
    cur[tid] = base;
    __syncthreads();
    for (int i = e0 + tid; i < e1; i += 256) {
        int p = pairs[i];
        int pos = atomicAdd(&cur[(p >> 16) & 0xff], 1);
        colu[pos] = (unsigned short)(p & 0xffff);
    }
}

// ====== fused layer 1: 4-edge-batched fp8-X gather -> 2x MFMA -> store ======
#define TLS 264
#define K1S 72
__global__ __launch_bounds__(512, 8) void k_layer1(const unsigned short* __restrict__ Xb,
                                                   const unsigned char* __restrict__ Xb8p,
                                                   const int* __restrict__ row_ptr,
                                                   const unsigned short* __restrict__ colu,
                                                   const unsigned short* __restrict__ WprojPack,
                                                   const float* __restrict__ bp,
                                                   const unsigned short* __restrict__ WlPack,
                                                   const float* __restrict__ bl,
                                                   const int* __restrict__ gid,
                                                   unsigned short* __restrict__ hout,
                                                   unsigned char* __restrict__ hout8,
                                                   float* __restrict__ GsumL) {
    __shared__ unsigned short tl[64 * TLS];
    unsigned short* tl1 = tl;          // overlay: 64*K1S = 4608 shorts
    float* redbase = (float*)(tl + 64 * K1S);   // dead zone of tl in phase 1
    __shared__ float bpm[64];
    __shared__ int gl[64];
    int tid = threadIdx.x;
    int w = tid >> 6, lane = tid & 63, quad = lane >> 4, l16 = lane & 15;
    int g = lane >> 4, sub = lane & 15;
    int m0 = blockIdx.x * 64;
    float* red = redbase + w * 256;

    // ---- phase 1: batched fp8 gather of X rows (4 edges per load) ----
    const unsigned int* X8 = (const unsigned int*)Xb8p;   // row stride 16 uints
    for (int rr = 0; rr < 8; rr++) {
        int r = w * 8 + rr;
        int v = m0 + r;
        f32x2 A = {0.f, 0.f};
        f32x2 Bv = {0.f, 0.f};
        int s = 0, e = 0;
        if (v < N_NODES) { s = row_ptr[v]; e = row_ptr[v + 1]; }
        int i = s;
        for (; i + 8 <= e; i += 8) {
            int ua = colu[i + g];
            int ub = colu[i + 4 + g];
            unsigned int pa = X8[ua * 16 + sub];
            unsigned int pb = X8[ub * 16 + sub];
            A  += pk2f<0>(pa) + pk2f<0>(pb);
            Bv += pk2f<1>(pa) + pk2f<1>(pb);
        }
        if (i + 4 <= e) {
            int ua = colu[i + g];
            unsigned int pa = X8[ua * 16 + sub];
            A += pk2f<0>(pa);
            Bv += pk2f<1>(pa);
            i += 4;
        }
        if (i < e) {   // wave-uniform guard; branchless per-lane tail
            int idx = i + g;
            int cl = (idx < e) ? idx : (e - 1);
            int ua = colu[cl];
            unsigned int pa = X8[ua * 16 + sub];
            float mvalid = (idx < e) ? 1.f : 0.f;
            f32x2 za = pk2f<0>(pa), zb = pk2f<1>(pa);
            A.x += mvalid * za.x; A.y += mvalid * za.y;
            Bv.x += mvalid * zb.x; Bv.y += mvalid * zb.y;
        }
        *(f32x4*)(red + g * 64 + sub * 4) = (f32x4){A.x, A.y, Bv.x, Bv.y};
        float ssum = (red[0 * 64 + lane] + red[1 * 64 + lane])
                   + (red[2 * 64 + lane] + red[3 * 64 + lane]);
        float val = 0.f;
        float mul = 1.f;
        if (v < N_NODES) {
            float inv = 0.f;
            if (e > s) { inv = 1.0f / (float)(e - s); mul = 2.f; }
            float self = (lane < XK) ? bf2f(Xb[(size_t)v * XK + lane]) : 0.f;
            val = self + inv * ssum;
        }
        tl1[r * K1S + lane] = (lane < XK) ? f2bf(val) : (unsigned short)0;
        if (lane == 0) bpm[r] = mul;
    }
    if (tid < 64) gl[tid] = (m0 + tid < N_NODES) ? gid[m0 + tid] : -1;
    __syncthreads();

    // ---- phase 2: MFMA stage 1 (A = tl1 64x64, B = WprojPack) ----
    int n0 = w * 32;
    f32x4 acc[4][2];
#pragma unroll
    for (int mt = 0; mt < 4; mt++) {
        acc[mt][0] = (f32x4){0.f, 0.f, 0.f, 0.f};
        acc[mt][1] = (f32x4){0.f, 0.f, 0.f, 0.f};
    }
#pragma unroll
    for (int ks = 0; ks < 2; ks++) {
        int kg = ks * 4 + quad;
        short8v bfr0 = *(const short8v*)(WprojPack + (size_t)(kg * 256 + n0 + l16) * 8);
        short8v bfr1 = *(const short8v*)(WprojPack + (size_t)(kg * 256 + n0 + 16 + l16) * 8);
#pragma unroll
        for (int mt = 0; mt < 4; mt++) {
            short8v afr = *(const short8v*)(tl1 + (mt * 16 + l16) * K1S + ks * 32 + quad * 8);
            acc[mt][0] = __builtin_amdgcn_mfma_f32_16x16x32_bf16(afr, bfr0, acc[mt][0], 0, 0, 0);
            acc[mt][1] = __builtin_amdgcn_mfma_f32_16x16x32_bf16(afr, bfr1, acc[mt][1], 0, 0, 0);
        }
    }
    __syncthreads();   // all tl1 reads complete before tl writes (overlay!)
#pragma unroll
    for (int nt = 0; nt < 2; nt++) {
        int colg = n0 + nt * 16 + l16;
        float bb = bp[colg];
#pragma unroll
        for (int mt = 0; mt < 4; mt++)
#pragma unroll
            for (int r = 0; r < 4; r++) {
                int row = mt * 16 + quad * 4 + r;
                tl[row * TLS + colg] = f2bf(acc[mt][nt][r] + bb * bpm[row]);
            }
    }
    __syncthreads();

    // ---- phase 3: MFMA stage 2 (A = tl 64x256, B = WlPack) ----
#pragma unroll
    for (int mt = 0; mt < 4; mt++) {
        acc[mt][0] = (f32x4){0.f, 0.f, 0.f, 0.f};
        acc[mt][1] = (f32x4){0.f, 0.f, 0.f, 0.f};
    }
#pragma unroll
    for (int ks = 0; ks < 8; ks++) {
        int kg = ks * 4 + quad;
        short8v bfr0 = *(const short8v*)(WlPack + (size_t)(kg * 256 + n0 + l16) * 8);
        short8v bfr1 = *(const short8v*)(WlPack + (size_t)(kg * 256 + n0 + 16 + l16) * 8);
#pragma unroll
        for (int mt = 0; mt < 4; mt++) {
            short8v afr = *(const short8v*)(tl + (mt * 16 + l16) * TLS + ks * 32 + quad * 8);
            acc[mt][0] = __builtin_amdgcn_mfma_f32_16x16x32_bf16(afr, bfr0, acc[mt][0], 0, 0, 0);
            acc[mt][1] = __builtin_amdgcn_mfma_f32_16x16x32_bf16(afr, bfr1, acc[mt][1], 0, 0, 0);
        }
    }
    __syncthreads();

    // ---- phase 4: epilogue ----
#pragma unroll
    for (int nt = 0; nt < 2; nt++) {
        int colg = n0 + nt * 16 + l16;
        float bb = bl[colg];
#pragma unroll
        for (int mt = 0; mt < 4; mt++)
#pragma unroll
            for (int r = 0; r < 4; r++)
                tl[(mt * 16 + quad * 4 + r) * TLS + colg] = f2bf(acc[mt][nt][r] + bb);
    }
    __syncthreads();

    // ---- phase 5a: coalesced stores (bf16 + fp8 mirror in plane layout) ----
    for (int i = tid; i < 64 * 64; i += 512) {
        int r = i >> 6, c4 = i & 63;
        int v = m0 + r;
        if (v < N_NODES) {
            ushort4 q = *(ushort4*)(tl + r * TLS + c4 * 4);
            ((ushort4*)hout)[(size_t)v * 64 + c4] = q;
            ((unsigned int*)hout8)[(size_t)(c4 >> 4) * PLANE_U + (size_t)v * 16 + (c4 & 15)] =
                pk4fp8(bf2f(q.x), bf2f(q.y), bf2f(q.z), bf2f(q.w));
        }
    }
    // ---- phase 5b: fused readout ----
    {
        int c = tid & 255;
        int r0 = (tid >> 8) * 32;
        float a2 = 0.f;
        int curg = gl[r0];
        for (int r = r0; r < r0 + 32; r++) {
            int gg = gl[r];
            if (gg < 0) break;
            if (gg != curg) {
                atomicAdd(&GsumL[curg * HIDDEN + c], a2);
                a2 = 0.f;
                curg = gg;
            }
            a2 += bf2f(tl[r * TLS + c]);
        }
        if (curg >= 0) atomicAdd(&GsumL[curg * HIDDEN + c], a2);
    }
}

// ====== fused layer (2,3): 4-pass column-slab fp8 gather -> MFMA -> store ===
// h8 layout: 4 planes of 64 cols (plane p contiguous, 3.2 MB, L2-resident).
// Pass p: lane-group g = lane&3 takes edge i+g; sub = lane>>2 covers cols
// p*64 + sub*4 + [0,4). Quad butterfly (shfl_xor 1,2) merges the 4 groups.
__global__ __launch_bounds__(512, 8) void k_layer(const unsigned short* __restrict__ h,
                                                  const unsigned char* __restrict__ h8,
                                                  const int* __restrict__ row_ptr,
                                                  const unsigned short* __restrict__ colu,
                                                  const unsigned short* __restrict__ Wpack,
                                                  const float* __restrict__ bias,
                                                  const int* __restrict__ gid,
                                                  unsigned short* __restrict__ hout,
                                                  unsigned char* __restrict__ hout8,
                                                  int write8,
                                                  float* __restrict__ GsumL) {
    __shared__ unsigned short tl[64 * TLS];   // 33792 B
    __shared__ int gl[64];
    int tid = threadIdx.x;
    int w = tid >> 6, lane = tid & 63, quad = lane >> 4, l16 = lane & 15;
    int g = lane & 3, sub = lane >> 2;        // slab-gather roles
    int m0 = blockIdx.x * 64;

    const unsigned int* h8v = (const unsigned int*)h8;
    const ushort4* hv = (const ushort4*)h;

    // ---- phase 1: 4 column-slab passes ----
    for (int p = 0; p < 4; p++) {
        const unsigned int* plane = h8v + (size_t)p * PLANE_U;
        for (int rr = 0; rr < 8; rr++) {
            int r = w * 8 + rr;
            int v = m0 + r;
            f32x2 A = {0.f, 0.f};   // cols p*64 + sub*4 + {0,1}
            f32x2 B = {0.f, 0.f};   // cols p*64 + sub*4 + {2,3}
            int s = 0, e = 0;
            if (v < N_NODES) { s = row_ptr[v]; e = row_ptr[v + 1]; }
            int i = s;
            for (; i + 8 <= e; i += 8) {
                int ua = colu[i + g];
                int ub = colu[i + 4 + g];
                unsigned int pa = plane[(size_t)ua * 16 + sub];
                unsigned int pb = plane[(size_t)ub * 16 + sub];
                A += pk2f<0>(pa) + pk2f<0>(pb);
                B += pk2f<1>(pa) + pk2f<1>(pb);
            }
            if (i + 4 <= e) {
                int ua = colu[i + g];
                unsigned int pa = plane[(size_t)ua * 16 + sub];
                A += pk2f<0>(pa);
                B += pk2f<1>(pa);
                i += 4;
            }
            if (i < e) {   // wave-uniform guard; branchless per-lane tail
                int idx = i + g;
                int cl = (idx < e) ? idx : (e - 1);
                int ua = colu[cl];
                unsigned int pa = plane[(size_t)ua * 16 + sub];
                float mvalid = (idx < e) ? 1.f : 0.f;
                f32x2 za = pk2f<0>(pa), zb = pk2f<1>(pa);
                A.x += mvalid * za.x; A.y += mvalid * za.y;
                B.x += mvalid * zb.x; B.y += mvalid * zb.y;
            }
            // quad butterfly reduce over g (uniform control flow, all lanes)
            A.x += __shfl_xor(A.x, 1); A.y += __shfl_xor(A.y, 1);
            B.x += __shfl_xor(B.x, 1); B.y += __shfl_xor(B.y, 1);
            A.x += __shfl_xor(A.x, 2); A.y += __shfl_xor(A.y, 2);
            B.x += __shfl_xor(B.x, 2); B.y += __shfl_xor(B.y, 2);
            if (g == 0) {
                ushort4 o = {0, 0, 0, 0};
                if (v < N_NODES) {
                    float inv = (e > s) ? 1.0f / (float)(e - s) : 0.0f;
                    ushort4 hs = hv[(size_t)v * 64 + p * 16 + sub];  // bf16 self
                    o.x = f2bf(bf2f(hs.x) + inv * A.x);
                    o.y = f2bf(bf2f(hs.y) + inv * A.y);
                    o.z = f2bf(bf2f(hs.z) + inv * B.x);
                    o.w = f2bf(bf2f(hs.w) + inv * B.y);
                }
                *(ushort4*)(tl + r * TLS + p * 64 + sub * 4) = o;
            }
        }
    }
    if (tid < 64) gl[tid] = (m0 + tid < N_NODES) ? gid[m0 + tid] : -1;
    __syncthreads();

    // ---- phase 2: MFMA ----
    int n0 = w * 32;
    f32x4 acc[4][2];
#pragma unroll
    for (int mt = 0; mt < 4; mt++) {
        acc[mt][0] = (f32x4){0.f, 0.f, 0.f, 0.f};
        acc[mt][1] = (f32x4){0.f, 0.f, 0.f, 0.f};
    }
#pragma unroll
    for (int ks = 0; ks < 8; ks++) {
        int kg = ks * 4 + quad;
        short8v bfr0 = *(const short8v*)(Wpack + (size_t)(kg * 256 + n0 + l16) * 8);
        short8v bfr1 = *(const short8v*)(Wpack + (size_t)(kg * 256 + n0 + 16 + l16) * 8);
#pragma unroll
        for (int mt = 0; mt < 4; mt++) {
            short8v afr = *(const short8v*)(tl + (mt * 16 + l16) * TLS + ks * 32 + quad * 8);
            acc[mt][0] = __builtin_amdgcn_mfma_f32_16x16x32_bf16(afr, bfr0, acc[mt][0], 0, 0, 0);
            acc[mt][1] = __builtin_amdgcn_mfma_f32_16x16x32_bf16(afr, bfr1, acc[mt][1], 0, 0, 0);
        }
    }
    __syncthreads();

    // ---- phase 3: epilogue ----
#pragma unroll
    for (int nt = 0; nt < 2; nt++) {
        int colg = n0 + nt * 16 + l16;
        float bb = bias[colg];
#pragma unroll
        for (int mt = 0; mt < 4; mt++)
#pragma unroll
            for (int r = 0; r < 4; r++)
                tl[(mt * 16 + quad * 4 + r) * TLS + colg] = f2bf(acc[mt][nt][r] + bb);
    }
    __syncthreads();

    // ---- phase 4a: coalesced stores (bf16 + optional fp8 plane mirror) ----
    for (int i = tid; i < 64 * 64; i += 512) {
        int r = i >> 6, c4 = i & 63;
        int v = m0 + r;
        if (v < N_NODES) {
            ushort4 q = *(ushort4*)(tl + r * TLS + c4 * 4);
            ((ushort4*)hout)[(size_t)v * 64 + c4] = q;
            if (write8)
                ((unsigned int*)hout8)[(size_t)(c4 >> 4) * PLANE_U + (size_t)v * 16 + (c4 & 15)] =
                    pk4fp8(bf2f(q.x), bf2f(q.y), bf2f(q.z), bf2f(q.w));
        }
    }
    // ---- phase 4b: fused readout ----
    {
        int c = tid & 255;
        int r0 = (tid >> 8) * 32;
        float a2 = 0.f;
        int curg = gl[r0];
        for (int r = r0; r < r0 + 32; r++) {
            int gg = gl[r];
            if (gg < 0) break;
            if (gg != curg) {
                atomicAdd(&GsumL[curg * HIDDEN + c], a2);
                a2 = 0.f;
                curg = gg;
            }
            a2 += bf2f(tl[r * TLS + c]);
        }
        if (curg >= 0) atomicAdd(&GsumL[curg * HIDDEN + c], a2);
    }
}

// ================= out[g] = (concat gmean) @ W_out + b_out ==================
__global__ __launch_bounds__(256) void k_out(const float* __restrict__ Gsum,
                                             const int* __restrict__ gcnt,
                                             const float* __restrict__ Wout,
                                             const float* __restrict__ bout,
                                             float* __restrict__ out) {
    int g = blockIdx.x;
    int c = threadIdx.x;
    __shared__ float gm[HIDDEN * CONV_NUMS];
    float invc = 1.0f / fmaxf((float)gcnt[g], 1.0f);
    for (int i = c; i < HIDDEN * CONV_NUMS; i += 256) {
        int l = i >> 8;
        int k = i & 255;
        gm[i] = Gsum[(size_t)l * N_GRAPHS * HIDDEN + g * HIDDEN + k] * invc;
    }
    __syncthreads();
    float acc = bout[c];
    const float4* gm4 = (const float4*)gm;
    for (int k0 = 0; k0 < HIDDEN * CONV_NUMS; k0 += 4) {
        float4 gv = gm4[k0 >> 2];
        acc += gv.x * Wout[(k0 + 0) * HIDDEN + c];
        acc += gv.y * Wout[(k0 + 1) * HIDDEN + c];
        acc += gv.z * Wout[(k0 + 2) * HIDDEN + c];
        acc += gv.w * Wout[(k0 + 3) * HIDDEN + c];
    }
    out[g * HIDDEN + c] = acc;
}

extern "C" void kernel_launch(void* const* d_in, const int* in_sizes, int n_in,
                              void* d_out, int out_size, void* d_ws, size_t ws_size,
                              hipStream_t stream) {
    const float* X    = (const float*)d_in[0];
    const int*   src  = (const int*)d_in[1];
    const int*   dst  = (const int*)d_in[2];
    const int*   gid  = (const int*)d_in[3];
    const float* Wp   = (const float*)d_in[4];
    const float* bp   = (const float*)d_in[5];
    const float* Wl   = (const float*)d_in[6];
    const float* bl   = (const float*)d_in[7];
    const float* Wout = (const float*)d_in[8];
    const float* bout = (const float*)d_in[9];
    float* out = (float*)d_out;

    char* ws = (char*)d_ws;
    size_t off = 0;
    auto alloc = [&](size_t bytes) {
        char* p = ws + off;
        off += (bytes + 255) & ~size_t(255);
        return p;
    };
    unsigned short* h         = (unsigned short*)alloc(sizeof(short) * N_NODES * HIDDEN);
    unsigned short* t         = (unsigned short*)alloc(sizeof(short) * N_NODES * HIDDEN);
    unsigned char*  h8a       = (unsigned char*)alloc((size_t)N_NODES * HIDDEN);
    unsigned char*  h8b       = (unsigned char*)alloc((size_t)N_NODES * HIDDEN);
    unsigned short* WlPack    = (unsigned short*)alloc(sizeof(short) * HIDDEN * HIDDEN);
    unsigned short* WprojPack = (unsigned short*)alloc(sizeof(short) * 8 * 256 * 8);
    unsigned short* Xb        = (unsigned short*)alloc(sizeof(short) * N_NODES * XK);
    unsigned char*  Xb8p      = (unsigned char*)alloc((size_t)N_NODES * XK8);
    int*   pairs   = (int*)alloc(sizeof(int) * N_EDGES);
    unsigned short* colu = (unsigned short*)alloc(sizeof(short) * N_EDGES);
    int*   row_ptr = (int*)alloc(sizeof(int) * (N_NODES + 1));
    int*   bucket_base   = (int*)alloc(sizeof(int) * (NBK + 1));
    int*   bucket_cursor = (int*)alloc(sizeof(int) * NBK);
    // contiguous zero region: bucket_cnt | gcnt | Gsum  -> one memset
    char*  zero0 = ws + off;
    int*   bucket_cnt = (int*)alloc(sizeof(int) * NBK);
    int*   gcnt       = (int*)alloc(sizeof(int) * N_GRAPHS);
    float* Gsum       = (float*)alloc(sizeof(float) * CONV_NUMS * N_GRAPHS * HIDDEN);
    size_t zero_bytes = (size_t)((char*)(Gsum + CONV_NUMS * N_GRAPHS * HIDDEN) - zero0);

    hipMemsetAsync(zero0, 0, zero_bytes, stream);

    {
        const int TOT8 = N_NODES * XK8;
        int ncast = (TOT8 + 2047) / 2048;
        k_build0<<<552 + ncast, 256, 0, stream>>>(dst, gid, Wl, Wp, X, bucket_cnt,
                                                  gcnt, WlPack, WprojPack, Xb, Xb8p);
    }
    k_bscan<<<1, 256, 0, stream>>>(bucket_cnt, bucket_base, bucket_cursor, row_ptr);
    k_passB<<<(N_EDGES + BCH - 1) / BCH, 256, 0, stream>>>(src, dst, bucket_cursor, pairs);
    k_passC<<<NBK, 256, 0, stream>>>(pairs, bucket_base, row_ptr, colu);

    // layer 1 (fused proj + conv1 + readout); writes bf16 h + fp8 planes h8a
    k_layer1<<<(N_NODES + 63) / 64, 512, 0, stream>>>(
        Xb, Xb8p, row_ptr, colu, WprojPack, bp, WlPack, bl, gid, h, h8a, Gsum);

    // layer 2: slab-gather fp8 planes h8a, self bf16 h -> t + h8b planes
    k_layer<<<(N_NODES + 63) / 64, 512, 0, stream>>>(
        h, h8a, row_ptr, colu, WlPack, bl, gid, t, h8b, 1,
        Gsum + (size_t)1 * N_GRAPHS * HIDDEN);

    // layer 3: slab-gather fp8 planes h8b, self bf16 t -> h (no mirror)
    k_layer<<<(N_NODES + 63) / 64, 512, 0, stream>>>(
        t, h8b, row_ptr, colu, WlPack, bl, gid, h, h8a, 0,
        Gsum + (size_t)2 * N_GRAPHS * HIDDEN);

    k_out<<<N_GRAPHS, 256, 0, stream>>>(Gsum, gcnt, Wout, bout, out);
}

// Round 14
// 355.841 us; speedup vs baseline: 1.4701x; 1.4701x over previous
//
#include <hip/hip_runtime.h>
#include <hip/hip_fp8.h>

#define N_NODES   50000
#define N_EDGES   1600000
#define N_GRAPHS  512
#define IN_SIZE   44
#define HIDDEN    256
#define CONV_NUMS 3
#define NBK       ((N_NODES + 255) / 256)   // 196 dst-buckets of 256 nodes
#define XK        48                        // bf16 X row stride (self-term)
#define XK8       64                        // fp8 X row stride (gather table, padded)

typedef __attribute__((ext_vector_type(8))) short short8v;   // 8 bf16 = 16 B
typedef __attribute__((ext_vector_type(4))) float f32x4;     // MFMA C/D frag
typedef __attribute__((ext_vector_type(2))) float f32x2;

__device__ __forceinline__ float bf2f(unsigned short u) {
    return __uint_as_float(((unsigned int)u) << 16);
}
__device__ __forceinline__ unsigned short f2bf(float f) {
    unsigned int u = __float_as_uint(f);
    unsigned int r = (u + 0x7fffu + ((u >> 16) & 1u)) >> 16;  // RNE
    return (unsigned short)r;
}

// ---- fp8 e4m3 (OCP on gfx950) helpers: HW cvt with HIP-type fallback ----
#if __has_builtin(__builtin_amdgcn_cvt_f32_fp8)
template <int SEL>
__device__ __forceinline__ float fp8tof(unsigned int w) {
    return __builtin_amdgcn_cvt_f32_fp8((int)w, SEL);
}
#else
template <int SEL>
__device__ __forceinline__ float fp8tof(unsigned int w) {
    __hip_fp8_e4m3 q;
    q.__x = (__hip_fp8_storage_t)((w >> (SEL * 8)) & 0xff);
    return (float)q;
}
#endif

// packed: word half HI(0/1) of w -> 2 floats (v_cvt_pk_f32_fp8, 1 inst)
#if __has_builtin(__builtin_amdgcn_cvt_pk_f32_fp8)
template <int HI>
__device__ __forceinline__ f32x2 pk2f(unsigned int w) {
    return __builtin_amdgcn_cvt_pk_f32_fp8((int)w, HI != 0);
}
#else
template <int HI>
__device__ __forceinline__ f32x2 pk2f(unsigned int w) {
    f32x2 r;
    r.x = fp8tof<2 * HI>(w);
    r.y = fp8tof<2 * HI + 1>(w);
    return r;
}
#endif

#if __has_builtin(__builtin_amdgcn_cvt_pk_fp8_f32)
__device__ __forceinline__ unsigned int pk4fp8(float f0, float f1, float f2, float f3) {
    int lo = __builtin_amdgcn_cvt_pk_fp8_f32(f0, f1, 0, false);
    return (unsigned int)__builtin_amdgcn_cvt_pk_fp8_f32(f2, f3, lo, true);
}
#else
__device__ __forceinline__ unsigned int pk4fp8(float f0, float f1, float f2, float f3) {
    __hip_fp8_e4m3 a(f0), b(f1), c(f2), d(f3);
    return (unsigned int)a.__x | ((unsigned int)b.__x << 8) |
           ((unsigned int)c.__x << 16) | ((unsigned int)d.__x << 24);
}
#endif

__device__ __forceinline__ unsigned char f2fp8(float f) {
    return (unsigned char)(pk4fp8(f, 0.f, 0.f, 0.f) & 0xff);
}

// ========== fused: bucket/graph histograms + weight pack + X cast ===========
// blocks [0,512): histograms; [512,544): WlPack; [544,552): WprojPack;
// [552, 552+ncast): Xb (bf16, stride 48) + Xb8p (fp8, stride 64) cast.
__global__ __launch_bounds__(256) void k_build0(const int* __restrict__ dst,
                                                const int* __restrict__ gid,
                                                const float* __restrict__ Wl,
                                                const float* __restrict__ Wproj,
                                                const float* __restrict__ X,
                                                int* __restrict__ bucket_cnt,
                                                int* __restrict__ gcnt,
                                                unsigned short* __restrict__ WlPack,
                                                unsigned short* __restrict__ WprojPack,
                                                unsigned short* __restrict__ Xb,
                                                unsigned char* __restrict__ Xb8p) {
    int b = blockIdx.x;
    int tid = threadIdx.x;
    if (b < 512) {
        __shared__ int hb[NBK];
        __shared__ int hg[N_GRAPHS];
        for (int i = tid; i < NBK; i += 256) hb[i] = 0;
        for (int i = tid; i < N_GRAPHS; i += 256) hg[i] = 0;
        __syncthreads();
        int t = b * 256 + tid;
        int stride = 512 * 256;
        for (int e = t; e < N_EDGES; e += stride) atomicAdd(&hb[dst[e] >> 8], 1);
        for (int v = t; v < N_NODES; v += stride) atomicAdd(&hg[gid[v]], 1);
        __syncthreads();
        for (int i = tid; i < NBK; i += 256) if (hb[i]) atomicAdd(&bucket_cnt[i], hb[i]);
        for (int i = tid; i < N_GRAPHS; i += 256) if (hg[i]) atomicAdd(&gcnt[i], hg[i]);
    } else if (b < 544) {               // WlPack: 8192 frags
        int i = (b - 512) * 256 + tid;
        int kg = i >> 8, n = i & 255;
        short8v v;
#pragma unroll
        for (int j = 0; j < 8; j++) v[j] = (short)f2bf(Wl[(kg * 8 + j) * HIDDEN + n]);
        *(short8v*)(WlPack + (size_t)(kg * 256 + n) * 8) = v;
    } else if (b < 552) {               // WprojPack: kg in [0,8), zero-pad k>=44
        int i = (b - 544) * 256 + tid;
        int kg = i >> 8, n = i & 255;
        short8v v;
#pragma unroll
        for (int j = 0; j < 8; j++) {
            int k = kg * 8 + j;
            v[j] = (k < IN_SIZE) ? (short)f2bf(Wproj[k * HIDDEN + n]) : (short)0;
        }
        *(short8v*)(WprojPack + (size_t)(kg * 256 + n) * 8) = v;
    } else {                            // Xb8p: N x 64 fp8 (+ Xb: N x 48 bf16)
        const int TOT8 = N_NODES * XK8;
        int id0 = (b - 552) * 2048 + tid;
#pragma unroll
        for (int j = 0; j < 8; j++) {
            int id = id0 + j * 256;
            if (id < TOT8) {
                int row = id >> 6, c = id & 63;
                float val = (c < IN_SIZE) ? X[row * IN_SIZE + c] : 0.f;
                Xb8p[id] = f2fp8(val);
                if (c < XK) Xb[(size_t)row * XK + c] = f2bf(val);
            }
        }
    }
}

__global__ void k_bscan(const int* __restrict__ bucket_cnt, int* __restrict__ bucket_base,
                        int* __restrict__ bucket_cursor, int* __restrict__ row_ptr) {
    __shared__ int s[256];
    int t = threadIdx.x;
    int v = (t < NBK) ? bucket_cnt[t] : 0;
    s[t] = v;
    __syncthreads();
    for (int off = 1; off < 256; off <<= 1) {
        int a = (t >= off) ? s[t - off] : 0;
        __syncthreads();
        s[t] += a;
        __syncthreads();
    }
    if (t < NBK) {
        int base = s[t] - v;
        bucket_base[t] = base;
        bucket_cursor[t] = base;
    }
    if (t == 0) {
        bucket_base[NBK] = N_EDGES;
        row_ptr[N_NODES] = N_EDGES;
    }
}

#define BCH 8192
__global__ __launch_bounds__(256) void k_passB(const int* __restrict__ src,
                                               const int* __restrict__ dst,
                                               int* __restrict__ bucket_cursor,
                                               int* __restrict__ pairs) {
    __shared__ int hist[NBK];
    __shared__ int excl[NBK];
    __shared__ int cur[NBK];
    __shared__ int gbase[NBK];
    __shared__ int lp[BCH];
    __shared__ int sc[256];
    int tid = threadIdx.x;
    int e0 = blockIdx.x * BCH;
    int cnt = min(BCH, N_EDGES - e0);
    for (int i = tid; i < NBK; i += 256) hist[i] = 0;
    __syncthreads();
    for (int i = tid; i < cnt; i += 256) atomicAdd(&hist[dst[e0 + i] >> 8], 1);
    __syncthreads();
    int hv = (tid < NBK) ? hist[tid] : 0;
    sc[tid] = hv;
    __syncthreads();
    for (int off = 1; off < 256; off <<= 1) {
        int a = (tid >= off) ? sc[tid - off] : 0;
        __syncthreads();
        sc[tid] += a;
        __syncthreads();
    }
    if (tid < NBK) {
        excl[tid] = sc[tid] - hv;
        cur[tid]  = sc[tid] - hv;
    }
    __syncthreads();
    for (int i = tid; i < cnt; i += 256) {
        int d = dst[e0 + i];
        int b = d >> 8;
        int pos = atomicAdd(&cur[b], 1);
        lp[pos] = (b << 24) | ((d & 255) << 16) | src[e0 + i];
    }
    __syncthreads();
    if (tid < NBK && hist[tid] > 0)
        gbase[tid] = atomicAdd(&bucket_cursor[tid], hist[tid]);
    __syncthreads();
    for (int i = tid; i < cnt; i += 256) {
        int p = lp[i];
        int b = (p >> 24) & 0xff;
        pairs[gbase[b] + (i - excl[b])] = p;
    }
}

__global__ __launch_bounds__(256) void k_passC(const int* __restrict__ pairs,
                                               const int* __restrict__ bucket_base,
                                               int* __restrict__ row_ptr,
                                               unsigned short* __restrict__ colu) {
    __shared__ int hist[256];
    __shared__ int cur[256];
    __shared__ int sc[256];
    int b = blockIdx.x;
    int tid = threadIdx.x;
    int v0 = b << 8;
    int e0 = bucket_base[b], e1 = bucket_base[b + 1];
    hist[tid] = 0;
    __syncthreads();
    for (int i = e0 + tid; i < e1; i += 256) atomicAdd(&hist[(pairs[i] >> 16) & 0xff], 1);
    __syncthreads();
    int hv = hist[tid];
    sc[tid] = hv;
    __syncthreads();
    for (int off = 1; off < 256; off <<= 1) {
        int a = (tid >= off) ? sc[tid - off] : 0;
        __syncthreads();
        sc[tid] += a;
        __syncthreads();
    }
    int base = e0 + sc[tid] - hv;
    int v = v0 + tid;
    if (v < N_NODES) row_ptr[v] = base;
    cur[tid] = base;
    __syncthreads();
    for (int i = e0 + tid; i < e1; i += 256) {
        int p = pairs[i];
        int pos = atomicAdd(&cur[(p >> 16) & 0xff], 1);
        colu[pos] = (unsigned short)(p & 0xffff);
    }
}

// ====== fused layer 1: 4-edge-batched fp8-X gather -> 2x MFMA -> store ======
// Gather: lane-group g = lane>>4 handles edge i+g; sub = lane&15 covers cols
// [sub*4, sub*4+4) of the 64 B-padded fp8 X row (one wave-load = 4 edges).
// Cross-group combine via wave-local LDS exchange (scratch in tl's dead zone).
#define TLS 264
#define K1S 72
__global__ __launch_bounds__(512, 8) void k_layer1(const unsigned short* __restrict__ Xb,
                                                   const unsigned char* __restrict__ Xb8p,
                                                   const int* __restrict__ row_ptr,
                                                   const unsigned short* __restrict__ colu,
                                                   const unsigned short* __restrict__ WprojPack,
                                                   const float* __restrict__ bp,
                                                   const unsigned short* __restrict__ WlPack,
                                                   const float* __restrict__ bl,
                                                   const int* __restrict__ gid,
                                                   unsigned short* __restrict__ hout,
                                                   unsigned char* __restrict__ hout8,
                                                   float* __restrict__ GsumL) {
    __shared__ unsigned short tl[64 * TLS];
    unsigned short* tl1 = tl;          // overlay: 64*K1S = 4608 shorts
    float* redbase = (float*)(tl + 64 * K1S);   // dead zone of tl in phase 1
    __shared__ float bpm[64];
    __shared__ int gl[64];
    int tid = threadIdx.x;
    int w = tid >> 6, lane = tid & 63, quad = lane >> 4, l16 = lane & 15;
    int g = lane >> 4, sub = lane & 15;
    int m0 = blockIdx.x * 64;
    float* red = redbase + w * 256;

    // ---- phase 1: batched fp8 gather of X rows (4 edges per load) ----
    const unsigned int* X8 = (const unsigned int*)Xb8p;   // row stride 16 uints
    for (int rr = 0; rr < 8; rr++) {
        int r = w * 8 + rr;
        int v = m0 + r;
        f32x2 A = {0.f, 0.f};
        f32x2 Bv = {0.f, 0.f};
        int s = 0, e = 0;
        if (v < N_NODES) { s = row_ptr[v]; e = row_ptr[v + 1]; }
        int i = s;
        for (; i + 8 <= e; i += 8) {
            int ua = colu[i + g];
            int ub = colu[i + 4 + g];
            unsigned int pa = X8[ua * 16 + sub];
            unsigned int pb = X8[ub * 16 + sub];
            A  += pk2f<0>(pa) + pk2f<0>(pb);
            Bv += pk2f<1>(pa) + pk2f<1>(pb);
        }
        if (i + 4 <= e) {
            int ua = colu[i + g];
            unsigned int pa = X8[ua * 16 + sub];
            A += pk2f<0>(pa);
            Bv += pk2f<1>(pa);
            i += 4;
        }
        if (i < e) {   // wave-uniform guard; branchless per-lane tail
            int idx = i + g;
            int cl = (idx < e) ? idx : (e - 1);
            int ua = colu[cl];
            unsigned int pa = X8[ua * 16 + sub];
            float mvalid = (idx < e) ? 1.f : 0.f;
            f32x2 za = pk2f<0>(pa), zb = pk2f<1>(pa);
            A.x += mvalid * za.x; A.y += mvalid * za.y;
            Bv.x += mvalid * zb.x; Bv.y += mvalid * zb.y;
        }
        *(f32x4*)(red + g * 64 + sub * 4) = (f32x4){A.x, A.y, Bv.x, Bv.y};
        float ssum = (red[0 * 64 + lane] + red[1 * 64 + lane])
                   + (red[2 * 64 + lane] + red[3 * 64 + lane]);
        float val = 0.f;
        float mul = 1.f;
        if (v < N_NODES) {
            float inv = 0.f;
            if (e > s) { inv = 1.0f / (float)(e - s); mul = 2.f; }
            float self = (lane < XK) ? bf2f(Xb[(size_t)v * XK + lane]) : 0.f;
            val = self + inv * ssum;
        }
        tl1[r * K1S + lane] = (lane < XK) ? f2bf(val) : (unsigned short)0;
        if (lane == 0) bpm[r] = mul;
    }
    if (tid < 64) gl[tid] = (m0 + tid < N_NODES) ? gid[m0 + tid] : -1;
    __syncthreads();

    // ---- phase 2: MFMA stage 1 (A = tl1 64x64, B = WprojPack) ----
    int n0 = w * 32;
    f32x4 acc[4][2];
#pragma unroll
    for (int mt = 0; mt < 4; mt++) {
        acc[mt][0] = (f32x4){0.f, 0.f, 0.f, 0.f};
        acc[mt][1] = (f32x4){0.f, 0.f, 0.f, 0.f};
    }
#pragma unroll
    for (int ks = 0; ks < 2; ks++) {
        int kg = ks * 4 + quad;
        short8v bfr0 = *(const short8v*)(WprojPack + (size_t)(kg * 256 + n0 + l16) * 8);
        short8v bfr1 = *(const short8v*)(WprojPack + (size_t)(kg * 256 + n0 + 16 + l16) * 8);
#pragma unroll
        for (int mt = 0; mt < 4; mt++) {
            short8v afr = *(const short8v*)(tl1 + (mt * 16 + l16) * K1S + ks * 32 + quad * 8);
            acc[mt][0] = __builtin_amdgcn_mfma_f32_16x16x32_bf16(afr, bfr0, acc[mt][0], 0, 0, 0);
            acc[mt][1] = __builtin_amdgcn_mfma_f32_16x16x32_bf16(afr, bfr1, acc[mt][1], 0, 0, 0);
        }
    }
    __syncthreads();   // all tl1 reads complete before tl writes (overlay!)
#pragma unroll
    for (int nt = 0; nt < 2; nt++) {
        int colg = n0 + nt * 16 + l16;
        float bb = bp[colg];
#pragma unroll
        for (int mt = 0; mt < 4; mt++)
#pragma unroll
            for (int r = 0; r < 4; r++) {
                int row = mt * 16 + quad * 4 + r;
                tl[row * TLS + colg] = f2bf(acc[mt][nt][r] + bb * bpm[row]);
            }
    }
    __syncthreads();

    // ---- phase 3: MFMA stage 2 (A = tl 64x256, B = WlPack) ----
#pragma unroll
    for (int mt = 0; mt < 4; mt++) {
        acc[mt][0] = (f32x4){0.f, 0.f, 0.f, 0.f};
        acc[mt][1] = (f32x4){0.f, 0.f, 0.f, 0.f};
    }
#pragma unroll
    for (int ks = 0; ks < 8; ks++) {
        int kg = ks * 4 + quad;
        short8v bfr0 = *(const short8v*)(WlPack + (size_t)(kg * 256 + n0 + l16) * 8);
        short8v bfr1 = *(const short8v*)(WlPack + (size_t)(kg * 256 + n0 + 16 + l16) * 8);
#pragma unroll
        for (int mt = 0; mt < 4; mt++) {
            short8v afr = *(const short8v*)(tl + (mt * 16 + l16) * TLS + ks * 32 + quad * 8);
            acc[mt][0] = __builtin_amdgcn_mfma_f32_16x16x32_bf16(afr, bfr0, acc[mt][0], 0, 0, 0);
            acc[mt][1] = __builtin_amdgcn_mfma_f32_16x16x32_bf16(afr, bfr1, acc[mt][1], 0, 0, 0);
        }
    }
    __syncthreads();

    // ---- phase 4: epilogue ----
#pragma unroll
    for (int nt = 0; nt < 2; nt++) {
        int colg = n0 + nt * 16 + l16;
        float bb = bl[colg];
#pragma unroll
        for (int mt = 0; mt < 4; mt++)
#pragma unroll
            for (int r = 0; r < 4; r++)
                tl[(mt * 16 + quad * 4 + r) * TLS + colg] = f2bf(acc[mt][nt][r] + bb);
    }
    __syncthreads();

    // ---- phase 5a: coalesced stores (bf16 + fp8 mirror) ----
    for (int i = tid; i < 64 * 64; i += 512) {
        int r = i >> 6, c4 = i & 63;
        int v = m0 + r;
        if (v < N_NODES) {
            ushort4 q = *(ushort4*)(tl + r * TLS + c4 * 4);
            ((ushort4*)hout)[(size_t)v * 64 + c4] = q;
            ((unsigned int*)hout8)[(size_t)v * 64 + c4] =
                pk4fp8(bf2f(q.x), bf2f(q.y), bf2f(q.z), bf2f(q.w));
        }
    }
    // ---- phase 5b: fused readout ----
    {
        int c = tid & 255;
        int r0 = (tid >> 8) * 32;
        float a2 = 0.f;
        int curg = gl[r0];
        for (int r = r0; r < r0 + 32; r++) {
            int gg = gl[r];
            if (gg < 0) break;
            if (gg != curg) {
                atomicAdd(&GsumL[curg * HIDDEN + c], a2);
                a2 = 0.f;
                curg = gg;
            }
            a2 += bf2f(tl[r * TLS + c]);
        }
        if (curg >= 0) atomicAdd(&GsumL[curg * HIDDEN + c], a2);
    }
}

// ====== fused layer (2,3): fp8 gather (pk-cvt) -> MFMA -> store =============
__global__ __launch_bounds__(512, 8) void k_layer(const unsigned short* __restrict__ h,
                                                  const unsigned char* __restrict__ h8,
                                                  const int* __restrict__ row_ptr,
                                                  const unsigned short* __restrict__ colu,
                                                  const unsigned short* __restrict__ Wpack,
                                                  const float* __restrict__ bias,
                                                  const int* __restrict__ gid,
                                                  unsigned short* __restrict__ hout,
                                                  unsigned char* __restrict__ hout8,
                                                  int write8,
                                                  float* __restrict__ GsumL) {
    __shared__ unsigned short tl[64 * TLS];   // 33792 B
    __shared__ int gl[64];
    int tid = threadIdx.x;
    int w = tid >> 6, lane = tid & 63, quad = lane >> 4, l16 = lane & 15;
    int m0 = blockIdx.x * 64;

    // ---- phase 1: fp8 gather + mean; static 8 rows/wave; packed cvt/add ----
    const unsigned int* h8v = (const unsigned int*)h8;   // 4 fp8 per lane (4 B)
    const ushort4* hv = (const ushort4*)h;
    for (int rr = 0; rr < 8; rr++) {
        int r = w * 8 + rr;
        int v = m0 + r;
        f32x2 A = {0.f, 0.f};   // cols lane*4 + {0,1}
        f32x2 B = {0.f, 0.f};   // cols lane*4 + {2,3}
        if (v < N_NODES) {
            int s = row_ptr[v], e = row_ptr[v + 1];
            int i = s;
            for (; i + 8 <= e; i += 8) {
                int u0 = colu[i],     u1 = colu[i + 1];
                int u2 = colu[i + 2], u3 = colu[i + 3];
                int u4 = colu[i + 4], u5 = colu[i + 5];
                int u6 = colu[i + 6], u7 = colu[i + 7];
                unsigned int p0 = h8v[(size_t)u0 * 64 + lane];
                unsigned int p1 = h8v[(size_t)u1 * 64 + lane];
                unsigned int p2 = h8v[(size_t)u2 * 64 + lane];
                unsigned int p3 = h8v[(size_t)u3 * 64 + lane];
                unsigned int p4 = h8v[(size_t)u4 * 64 + lane];
                unsigned int p5 = h8v[(size_t)u5 * 64 + lane];
                unsigned int p6 = h8v[(size_t)u6 * 64 + lane];
                unsigned int p7 = h8v[(size_t)u7 * 64 + lane];
                A += (pk2f<0>(p0) + pk2f<0>(p1)) + (pk2f<0>(p2) + pk2f<0>(p3))
                   + (pk2f<0>(p4) + pk2f<0>(p5)) + (pk2f<0>(p6) + pk2f<0>(p7));
                B += (pk2f<1>(p0) + pk2f<1>(p1)) + (pk2f<1>(p2) + pk2f<1>(p3))
                   + (pk2f<1>(p4) + pk2f<1>(p5)) + (pk2f<1>(p6) + pk2f<1>(p7));
            }
            for (; i + 4 <= e; i += 4) {
                int u0 = colu[i], u1 = colu[i + 1], u2 = colu[i + 2], u3 = colu[i + 3];
                unsigned int p0 = h8v[(size_t)u0 * 64 + lane];
                unsigned int p1 = h8v[(size_t)u1 * 64 + lane];
                unsigned int p2 = h8v[(size_t)u2 * 64 + lane];
                unsigned int p3 = h8v[(size_t)u3 * 64 + lane];
                A += (pk2f<0>(p0) + pk2f<0>(p1)) + (pk2f<0>(p2) + pk2f<0>(p3));
                B += (pk2f<1>(p0) + pk2f<1>(p1)) + (pk2f<1>(p2) + pk2f<1>(p3));
            }
            for (; i < e; i++) {
                unsigned int p = h8v[(size_t)colu[i] * 64 + lane];
                A += pk2f<0>(p);
                B += pk2f<1>(p);
            }
            float inv = (e > s) ? 1.0f / (float)(e - s) : 0.0f;
            ushort4 hs = hv[(size_t)v * 64 + lane];   // self-term bf16
            A.x = bf2f(hs.x) + inv * A.x;
            A.y = bf2f(hs.y) + inv * A.y;
            B.x = bf2f(hs.z) + inv * B.x;
            B.y = bf2f(hs.w) + inv * B.y;
        }
        ushort4 o;
        o.x = f2bf(A.x); o.y = f2bf(A.y); o.z = f2bf(B.x); o.w = f2bf(B.y);
        *(ushort4*)(tl + r * TLS + lane * 4) = o;
    }
    if (tid < 64) gl[tid] = (m0 + tid < N_NODES) ? gid[m0 + tid] : -1;
    __syncthreads();

    // ---- phase 2: MFMA ----
    int n0 = w * 32;
    f32x4 acc[4][2];
#pragma unroll
    for (int mt = 0; mt < 4; mt++) {
        acc[mt][0] = (f32x4){0.f, 0.f, 0.f, 0.f};
        acc[mt][1] = (f32x4){0.f, 0.f, 0.f, 0.f};
    }
#pragma unroll
    for (int ks = 0; ks < 8; ks++) {
        int kg = ks * 4 + quad;
        short8v bfr0 = *(const short8v*)(Wpack + (size_t)(kg * 256 + n0 + l16) * 8);
        short8v bfr1 = *(const short8v*)(Wpack + (size_t)(kg * 256 + n0 + 16 + l16) * 8);
#pragma unroll
        for (int mt = 0; mt < 4; mt++) {
            short8v afr = *(const short8v*)(tl + (mt * 16 + l16) * TLS + ks * 32 + quad * 8);
            acc[mt][0] = __builtin_amdgcn_mfma_f32_16x16x32_bf16(afr, bfr0, acc[mt][0], 0, 0, 0);
            acc[mt][1] = __builtin_amdgcn_mfma_f32_16x16x32_bf16(afr, bfr1, acc[mt][1], 0, 0, 0);
        }
    }
    __syncthreads();

    // ---- phase 3: epilogue ----
#pragma unroll
    for (int nt = 0; nt < 2; nt++) {
        int colg = n0 + nt * 16 + l16;
        float bb = bias[colg];
#pragma unroll
        for (int mt = 0; mt < 4; mt++)
#pragma unroll
            for (int r = 0; r < 4; r++)
                tl[(mt * 16 + quad * 4 + r) * TLS + colg] = f2bf(acc[mt][nt][r] + bb);
    }
    __syncthreads();

    // ---- phase 4a: coalesced stores (bf16 + optional fp8 mirror) ----
    for (int i = tid; i < 64 * 64; i += 512) {
        int r = i >> 6, c4 = i & 63;
        int v = m0 + r;
        if (v < N_NODES) {
            ushort4 q = *(ushort4*)(tl + r * TLS + c4 * 4);
            ((ushort4*)hout)[(size_t)v * 64 + c4] = q;
            if (write8)
                ((unsigned int*)hout8)[(size_t)v * 64 + c4] =
                    pk4fp8(bf2f(q.x), bf2f(q.y), bf2f(q.z), bf2f(q.w));
        }
    }
    // ---- phase 4b: fused readout ----
    {
        int c = tid & 255;
        int r0 = (tid >> 8) * 32;
        float a2 = 0.f;
        int curg = gl[r0];
        for (int r = r0; r < r0 + 32; r++) {
            int g = gl[r];
            if (g < 0) break;
            if (g != curg) {
                atomicAdd(&GsumL[curg * HIDDEN + c], a2);
                a2 = 0.f;
                curg = g;
            }
            a2 += bf2f(tl[r * TLS + c]);
        }
        if (curg >= 0) atomicAdd(&GsumL[curg * HIDDEN + c], a2);
    }
}

// ================= out[g] = (concat gmean) @ W_out + b_out ==================
__global__ __launch_bounds__(256) void k_out(const float* __restrict__ Gsum,
                                             const int* __restrict__ gcnt,
                                             const float* __restrict__ Wout,
                                             const float* __restrict__ bout,
                                             float* __restrict__ out) {
    int g = blockIdx.x;
    int c = threadIdx.x;
    __shared__ float gm[HIDDEN * CONV_NUMS];
    float invc = 1.0f / fmaxf((float)gcnt[g], 1.0f);
    for (int i = c; i < HIDDEN * CONV_NUMS; i += 256) {
        int l = i >> 8;
        int k = i & 255;
        gm[i] = Gsum[(size_t)l * N_GRAPHS * HIDDEN + g * HIDDEN + k] * invc;
    }
    __syncthreads();
    float acc = bout[c];
    const float4* gm4 = (const float4*)gm;
    for (int k0 = 0; k0 < HIDDEN * CONV_NUMS; k0 += 4) {
        float4 gv = gm4[k0 >> 2];
        acc += gv.x * Wout[(k0 + 0) * HIDDEN + c];
        acc += gv.y * Wout[(k0 + 1) * HIDDEN + c];
        acc += gv.z * Wout[(k0 + 2) * HIDDEN + c];
        acc += gv.w * Wout[(k0 + 3) * HIDDEN + c];
    }
    out[g * HIDDEN + c] = acc;
}

extern "C" void kernel_launch(void* const* d_in, const int* in_sizes, int n_in,
                              void* d_out, int out_size, void* d_ws, size_t ws_size,
                              hipStream_t stream) {
    const float* X    = (const float*)d_in[0];
    const int*   src  = (const int*)d_in[1];
    const int*   dst  = (const int*)d_in[2];
    const int*   gid  = (const int*)d_in[3];
    const float* Wp   = (const float*)d_in[4];
    const float* bp   = (const float*)d_in[5];
    const float* Wl   = (const float*)d_in[6];
    const float* bl   = (const float*)d_in[7];
    const float* Wout = (const float*)d_in[8];
    const float* bout = (const float*)d_in[9];
    float* out = (float*)d_out;

    char* ws = (char*)d_ws;
    size_t off = 0;
    auto alloc = [&](size_t bytes) {
        char* p = ws + off;
        off += (bytes + 255) & ~size_t(255);
        return p;
    };
    unsigned short* h         = (unsigned short*)alloc(sizeof(short) * N_NODES * HIDDEN);
    unsigned short* t         = (unsigned short*)alloc(sizeof(short) * N_NODES * HIDDEN);
    unsigned char*  h8a       = (unsigned char*)alloc((size_t)N_NODES * HIDDEN);
    unsigned char*  h8b       = (unsigned char*)alloc((size_t)N_NODES * HIDDEN);
    unsigned short* WlPack    = (unsigned short*)alloc(sizeof(short) * HIDDEN * HIDDEN);
    unsigned short* WprojPack = (unsigned short*)alloc(sizeof(short) * 8 * 256 * 8);
    unsigned short* Xb        = (unsigned short*)alloc(sizeof(short) * N_NODES * XK);
    unsigned char*  Xb8p      = (unsigned char*)alloc((size_t)N_NODES * XK8);
    int*   pairs   = (int*)alloc(sizeof(int) * N_EDGES);
    unsigned short* colu = (unsigned short*)alloc(sizeof(short) * N_EDGES);
    int*   row_ptr = (int*)alloc(sizeof(int) * (N_NODES + 1));
    int*   bucket_base   = (int*)alloc(sizeof(int) * (NBK + 1));
    int*   bucket_cursor = (int*)alloc(sizeof(int) * NBK);
    // contiguous zero region: bucket_cnt | gcnt | Gsum  -> one memset
    char*  zero0 = ws + off;
    int*   bucket_cnt = (int*)alloc(sizeof(int) * NBK);
    int*   gcnt       = (int*)alloc(sizeof(int) * N_GRAPHS);
    float* Gsum       = (float*)alloc(sizeof(float) * CONV_NUMS * N_GRAPHS * HIDDEN);
    size_t zero_bytes = (size_t)((char*)(Gsum + CONV_NUMS * N_GRAPHS * HIDDEN) - zero0);

    hipMemsetAsync(zero0, 0, zero_bytes, stream);

    {
        const int TOT8 = N_NODES * XK8;
        int ncast = (TOT8 + 2047) / 2048;
        k_build0<<<552 + ncast, 256, 0, stream>>>(dst, gid, Wl, Wp, X, bucket_cnt,
                                                  gcnt, WlPack, WprojPack, Xb, Xb8p);
    }
    k_bscan<<<1, 256, 0, stream>>>(bucket_cnt, bucket_base, bucket_cursor, row_ptr);
    k_passB<<<(N_EDGES + BCH - 1) / BCH, 256, 0, stream>>>(src, dst, bucket_cursor, pairs);
    k_passC<<<NBK, 256, 0, stream>>>(pairs, bucket_base, row_ptr, colu);

    // layer 1 (fused proj + conv1 + readout); writes bf16 h + fp8 mirror h8a
    k_layer1<<<(N_NODES + 63) / 64, 512, 0, stream>>>(
        Xb, Xb8p, row_ptr, colu, WprojPack, bp, WlPack, bl, gid, h, h8a, Gsum);

    // layer 2: gather fp8(h8a), self bf16 h -> t + h8b
    k_layer<<<(N_NODES + 63) / 64, 512, 0, stream>>>(
        h, h8a, row_ptr, colu, WlPack, bl, gid, t, h8b, 1,
        Gsum + (size_t)1 * N_GRAPHS * HIDDEN);

    // layer 3: gather fp8(h8b), self bf16 t -> h (no fp8 mirror needed)
    k_layer<<<(N_NODES + 63) / 64, 512, 0, stream>>>(
        t, h8b, row_ptr, colu, WlPack, bl, gid, h, h8a, 0,
        Gsum + (size_t)2 * N_GRAPHS * HIDDEN);

    k_out<<<N_GRAPHS, 256, 0, stream>>>(Gsum, gcnt, Wout, bout, out);
}

// Round 15
// 337.626 us; speedup vs baseline: 1.5494x; 1.0539x over previous
//
#include <hip/hip_runtime.h>
#include <hip/hip_fp8.h>

#define N_NODES   50000
#define N_EDGES   1600000
#define N_GRAPHS  512
#define IN_SIZE   44
#define HIDDEN    256
#define CONV_NUMS 3
#define NBK       ((N_NODES + 255) / 256)   // 196 dst-buckets of 256 nodes
#define CAP       16384                     // fixed colu/pairs stride per bucket
#define XK        48                        // bf16 X row stride (self-term)
#define XK8       64                        // fp8 X row stride (gather table, padded)

typedef __attribute__((ext_vector_type(8))) short short8v;            // 8 bf16 = 16 B
typedef __attribute__((ext_vector_type(8))) unsigned short ushort8v;  // 8 u16 = 16 B
typedef __attribute__((ext_vector_type(4))) float f32x4;              // MFMA C/D frag
typedef __attribute__((ext_vector_type(2))) float f32x2;

__device__ __forceinline__ float bf2f(unsigned short u) {
    return __uint_as_float(((unsigned int)u) << 16);
}
__device__ __forceinline__ unsigned short f2bf(float f) {
    unsigned int u = __float_as_uint(f);
    unsigned int r = (u + 0x7fffu + ((u >> 16) & 1u)) >> 16;  // RNE
    return (unsigned short)r;
}

// ---- fp8 e4m3 (OCP on gfx950) helpers: HW cvt with HIP-type fallback ----
#if __has_builtin(__builtin_amdgcn_cvt_f32_fp8)
template <int SEL>
__device__ __forceinline__ float fp8tof(unsigned int w) {
    return __builtin_amdgcn_cvt_f32_fp8((int)w, SEL);
}
#else
template <int SEL>
__device__ __forceinline__ float fp8tof(unsigned int w) {
    __hip_fp8_e4m3 q;
    q.__x = (__hip_fp8_storage_t)((w >> (SEL * 8)) & 0xff);
    return (float)q;
}
#endif

#if __has_builtin(__builtin_amdgcn_cvt_pk_f32_fp8)
template <int HI>
__device__ __forceinline__ f32x2 pk2f(unsigned int w) {
    return __builtin_amdgcn_cvt_pk_f32_fp8((int)w, HI != 0);
}
#else
template <int HI>
__device__ __forceinline__ f32x2 pk2f(unsigned int w) {
    f32x2 r;
    r.x = fp8tof<2 * HI>(w);
    r.y = fp8tof<2 * HI + 1>(w);
    return r;
}
#endif

#if __has_builtin(__builtin_amdgcn_cvt_pk_fp8_f32)
__device__ __forceinline__ unsigned int pk4fp8(float f0, float f1, float f2, float f3) {
    int lo = __builtin_amdgcn_cvt_pk_fp8_f32(f0, f1, 0, false);
    return (unsigned int)__builtin_amdgcn_cvt_pk_fp8_f32(f2, f3, lo, true);
}
#else
__device__ __forceinline__ unsigned int pk4fp8(float f0, float f1, float f2, float f3) {
    __hip_fp8_e4m3 a(f0), b(f1), c(f2), d(f3);
    return (unsigned int)a.__x | ((unsigned int)b.__x << 8) |
           ((unsigned int)c.__x << 16) | ((unsigned int)d.__x << 24);
}
#endif

__device__ __forceinline__ unsigned char f2fp8(float f) {
    return (unsigned char)(pk4fp8(f, 0.f, 0.f, 0.f) & 0xff);
}

// ========= fused: graph histogram + cursor init + weight pack + X cast ======
// blocks [0,64): gcnt histogram (+ block 0 inits bucket_cursor[b]=b*CAP);
// [64,96): WlPack; [96,104): WprojPack; [104, 104+ncast): Xb/Xb8p cast.
__global__ __launch_bounds__(256) void k_build0(const int* __restrict__ gid,
                                                const float* __restrict__ Wl,
                                                const float* __restrict__ Wproj,
                                                const float* __restrict__ X,
                                                int* __restrict__ bucket_cursor,
                                                int* __restrict__ gcnt,
                                                unsigned short* __restrict__ WlPack,
                                                unsigned short* __restrict__ WprojPack,
                                                unsigned short* __restrict__ Xb,
                                                unsigned char* __restrict__ Xb8p) {
    int b = blockIdx.x;
    int tid = threadIdx.x;
    if (b < 64) {
        if (b == 0 && tid < NBK) bucket_cursor[tid] = tid * CAP;
        __shared__ int hg[N_GRAPHS];
        for (int i = tid; i < N_GRAPHS; i += 256) hg[i] = 0;
        __syncthreads();
        int t = b * 256 + tid;
        int stride = 64 * 256;
        for (int v = t; v < N_NODES; v += stride) atomicAdd(&hg[gid[v]], 1);
        __syncthreads();
        for (int i = tid; i < N_GRAPHS; i += 256) if (hg[i]) atomicAdd(&gcnt[i], hg[i]);
    } else if (b < 96) {                // WlPack: 8192 frags
        int i = (b - 64) * 256 + tid;
        int kg = i >> 8, n = i & 255;
        short8v v;
#pragma unroll
        for (int j = 0; j < 8; j++) v[j] = (short)f2bf(Wl[(kg * 8 + j) * HIDDEN + n]);
        *(short8v*)(WlPack + (size_t)(kg * 256 + n) * 8) = v;
    } else if (b < 104) {               // WprojPack: kg in [0,8), zero-pad k>=44
        int i = (b - 96) * 256 + tid;
        int kg = i >> 8, n = i & 255;
        short8v v;
#pragma unroll
        for (int j = 0; j < 8; j++) {
            int k = kg * 8 + j;
            v[j] = (k < IN_SIZE) ? (short)f2bf(Wproj[k * HIDDEN + n]) : (short)0;
        }
        *(short8v*)(WprojPack + (size_t)(kg * 256 + n) * 8) = v;
    } else {                            // Xb8p: N x 64 fp8 (+ Xb: N x 48 bf16)
        const int TOT8 = N_NODES * XK8;
        int id0 = (b - 104) * 2048 + tid;
#pragma unroll
        for (int j = 0; j < 8; j++) {
            int id = id0 + j * 256;
            if (id < TOT8) {
                int row = id >> 6, c = id & 63;
                float val = (c < IN_SIZE) ? X[row * IN_SIZE + c] : 0.f;
                Xb8p[id] = f2fp8(val);
                if (c < XK) Xb[(size_t)row * XK + c] = f2bf(val);
            }
        }
    }
}

// Pass B: LDS-sort 8192-edge chunks by bucket; write packed (b,ldst,src) runs
// into fixed-stride bucket regions of `pairs` via bucket_cursor reservations.
#define BCH 8192
__global__ __launch_bounds__(256) void k_passB(const int* __restrict__ src,
                                               const int* __restrict__ dst,
                                               int* __restrict__ bucket_cursor,
                                               int* __restrict__ pairs) {
    __shared__ int hist[NBK];
    __shared__ int excl[NBK];
    __shared__ int cur[NBK];
    __shared__ int gbase[NBK];
    __shared__ int lp[BCH];
    __shared__ int sc[256];
    int tid = threadIdx.x;
    int e0 = blockIdx.x * BCH;
    int cnt = min(BCH, N_EDGES - e0);
    for (int i = tid; i < NBK; i += 256) hist[i] = 0;
    __syncthreads();
    for (int i = tid; i < cnt; i += 256) atomicAdd(&hist[dst[e0 + i] >> 8], 1);
    __syncthreads();
    int hv = (tid < NBK) ? hist[tid] : 0;
    sc[tid] = hv;
    __syncthreads();
    for (int off = 1; off < 256; off <<= 1) {
        int a = (tid >= off) ? sc[tid - off] : 0;
        __syncthreads();
        sc[tid] += a;
        __syncthreads();
    }
    if (tid < NBK) {
        excl[tid] = sc[tid] - hv;
        cur[tid]  = sc[tid] - hv;
    }
    __syncthreads();
    for (int i = tid; i < cnt; i += 256) {
        int d = dst[e0 + i];
        int b = d >> 8;
        int pos = atomicAdd(&cur[b], 1);
        lp[pos] = (b << 24) | ((d & 255) << 16) | src[e0 + i];
    }
    __syncthreads();
    if (tid < NBK && hist[tid] > 0)
        gbase[tid] = atomicAdd(&bucket_cursor[tid], hist[tid]);
    __syncthreads();
    for (int i = tid; i < cnt; i += 256) {
        int p = lp[i];
        int b = (p >> 24) & 0xff;
        pairs[gbase[b] + (i - excl[b])] = p;
    }
}

// Pass C: one block per bucket -> packed row_ptr (start | deg<<24) + colu.
// Row starts padded to multiples of 8 entries (16 B-aligned ushort8 loads).
__global__ __launch_bounds__(256) void k_passC(const int* __restrict__ pairs,
                                               const int* __restrict__ bucket_cursor,
                                               int* __restrict__ row_ptr,
                                               unsigned short* __restrict__ colu) {
    __shared__ int hist[256];
    __shared__ int cur[256];
    __shared__ int sc[256];
    int b = blockIdx.x;
    int tid = threadIdx.x;
    int v0 = b << 8;
    int e0 = b * CAP;
    int e1 = bucket_cursor[b];          // base + count after passB
    hist[tid] = 0;
    __syncthreads();
    for (int i = e0 + tid; i < e1; i += 256) atomicAdd(&hist[(pairs[i] >> 16) & 0xff], 1);
    __syncthreads();
    int hv = hist[tid];
    int hv8 = (hv + 7) & ~7;            // 8-aligned row span
    sc[tid] = hv8;
    __syncthreads();
    for (int off = 1; off < 256; off <<= 1) {
        int a = (tid >= off) ? sc[tid - off] : 0;
        __syncthreads();
        sc[tid] += a;
        __syncthreads();
    }
    int base = e0 + sc[tid] - hv8;
    int v = v0 + tid;
    if (v < N_NODES) row_ptr[v] = base | (hv << 24);
    cur[tid] = base;
    __syncthreads();
    for (int i = e0 + tid; i < e1; i += 256) {
        int p = pairs[i];
        int pos = atomicAdd(&cur[(p >> 16) & 0xff], 1);
        colu[pos] = (unsigned short)(p & 0xffff);
    }
}

// ====== fused layer 1: 4-edge-batched fp8-X gather -> 2x MFMA -> store ======
#define TLS 264
#define K1S 72
__global__ __launch_bounds__(512, 8) void k_layer1(const unsigned short* __restrict__ Xb,
                                                   const unsigned char* __restrict__ Xb8p,
                                                   const int* __restrict__ row_ptr,
                                                   const unsigned short* __restrict__ colu,
                                                   const unsigned short* __restrict__ WprojPack,
                                                   const float* __restrict__ bp,
                                                   const unsigned short* __restrict__ WlPack,
                                                   const float* __restrict__ bl,
                                                   const int* __restrict__ gid,
                                                   unsigned short* __restrict__ hout,
                                                   unsigned char* __restrict__ hout8,
                                                   float* __restrict__ GsumL) {
    __shared__ unsigned short tl[64 * TLS];
    unsigned short* tl1 = tl;          // overlay: 64*K1S = 4608 shorts
    float* redbase = (float*)(tl + 64 * K1S);   // dead zone of tl in phase 1
    __shared__ float bpm[64];
    __shared__ int gl[64];
    int tid = threadIdx.x;
    int w = tid >> 6, lane = tid & 63, quad = lane >> 4, l16 = lane & 15;
    int g = lane >> 4, sub = lane & 15;
    int m0 = blockIdx.x * 64;
    float* red = redbase + w * 256;

    // ---- phase 1: batched fp8 gather of X rows (4 edges per load) ----
    const unsigned int* X8 = (const unsigned int*)Xb8p;   // row stride 16 uints
    for (int rr = 0; rr < 8; rr++) {
        int r = w * 8 + rr;
        int v = m0 + r;
        f32x2 A = {0.f, 0.f};
        f32x2 Bv = {0.f, 0.f};
        int s = 0, e = 0;
        if (v < N_NODES) {
            int rp = row_ptr[v];
            s = rp & 0xffffff;
            e = s + (int)(((unsigned int)rp) >> 24);
        }
        int i = s;
        for (; i + 8 <= e; i += 8) {
            int ua = colu[i + g];
            int ub = colu[i + 4 + g];
            unsigned int pa = X8[ua * 16 + sub];
            unsigned int pb = X8[ub * 16 + sub];
            A  += pk2f<0>(pa) + pk2f<0>(pb);
            Bv += pk2f<1>(pa) + pk2f<1>(pb);
        }
        if (i + 4 <= e) {
            int ua = colu[i + g];
            unsigned int pa = X8[ua * 16 + sub];
            A += pk2f<0>(pa);
            Bv += pk2f<1>(pa);
            i += 4;
        }
        if (i < e) {   // wave-uniform guard; branchless per-lane tail
            int idx = i + g;
            int cl = (idx < e) ? idx : (e - 1);
            int ua = colu[cl];
            unsigned int pa = X8[ua * 16 + sub];
            float mvalid = (idx < e) ? 1.f : 0.f;
            f32x2 za = pk2f<0>(pa), zb = pk2f<1>(pa);
            A.x += mvalid * za.x; A.y += mvalid * za.y;
            Bv.x += mvalid * zb.x; Bv.y += mvalid * zb.y;
        }
        *(f32x4*)(red + g * 64 + sub * 4) = (f32x4){A.x, A.y, Bv.x, Bv.y};
        float ssum = (red[0 * 64 + lane] + red[1 * 64 + lane])
                   + (red[2 * 64 + lane] + red[3 * 64 + lane]);
        float val = 0.f;
        float mul = 1.f;
        if (v < N_NODES) {
            float inv = 0.f;
            if (e > s) { inv = 1.0f / (float)(e - s); mul = 2.f; }
            float self = (lane < XK) ? bf2f(Xb[(size_t)v * XK + lane]) : 0.f;
            val = self + inv * ssum;
        }
        tl1[r * K1S + lane] = (lane < XK) ? f2bf(val) : (unsigned short)0;
        if (lane == 0) bpm[r] = mul;
    }
    if (tid < 64) gl[tid] = (m0 + tid < N_NODES) ? gid[m0 + tid] : -1;
    __syncthreads();

    // ---- phase 2: MFMA stage 1 (A = tl1 64x64, B = WprojPack) ----
    int n0 = w * 32;
    f32x4 acc[4][2];
#pragma unroll
    for (int mt = 0; mt < 4; mt++) {
        acc[mt][0] = (f32x4){0.f, 0.f, 0.f, 0.f};
        acc[mt][1] = (f32x4){0.f, 0.f, 0.f, 0.f};
    }
#pragma unroll
    for (int ks = 0; ks < 2; ks++) {
        int kg = ks * 4 + quad;
        short8v bfr0 = *(const short8v*)(WprojPack + (size_t)(kg * 256 + n0 + l16) * 8);
        short8v bfr1 = *(const short8v*)(WprojPack + (size_t)(kg * 256 + n0 + 16 + l16) * 8);
#pragma unroll
        for (int mt = 0; mt < 4; mt++) {
            short8v afr = *(const short8v*)(tl1 + (mt * 16 + l16) * K1S + ks * 32 + quad * 8);
            acc[mt][0] = __builtin_amdgcn_mfma_f32_16x16x32_bf16(afr, bfr0, acc[mt][0], 0, 0, 0);
            acc[mt][1] = __builtin_amdgcn_mfma_f32_16x16x32_bf16(afr, bfr1, acc[mt][1], 0, 0, 0);
        }
    }
    __syncthreads();   // all tl1 reads complete before tl writes (overlay!)
#pragma unroll
    for (int nt = 0; nt < 2; nt++) {
        int colg = n0 + nt * 16 + l16;
        float bb = bp[colg];
#pragma unroll
        for (int mt = 0; mt < 4; mt++)
#pragma unroll
            for (int r = 0; r < 4; r++) {
                int row = mt * 16 + quad * 4 + r;
                tl[row * TLS + colg] = f2bf(acc[mt][nt][r] + bb * bpm[row]);
            }
    }
    __syncthreads();

    // ---- phase 3: MFMA stage 2 (A = tl 64x256, B = WlPack) ----
#pragma unroll
    for (int mt = 0; mt < 4; mt++) {
        acc[mt][0] = (f32x4){0.f, 0.f, 0.f, 0.f};
        acc[mt][1] = (f32x4){0.f, 0.f, 0.f, 0.f};
    }
#pragma unroll
    for (int ks = 0; ks < 8; ks++) {
        int kg = ks * 4 + quad;
        short8v bfr0 = *(const short8v*)(WlPack + (size_t)(kg * 256 + n0 + l16) * 8);
        short8v bfr1 = *(const short8v*)(WlPack + (size_t)(kg * 256 + n0 + 16 + l16) * 8);
#pragma unroll
        for (int mt = 0; mt < 4; mt++) {
            short8v afr = *(const short8v*)(tl + (mt * 16 + l16) * TLS + ks * 32 + quad * 8);
            acc[mt][0] = __builtin_amdgcn_mfma_f32_16x16x32_bf16(afr, bfr0, acc[mt][0], 0, 0, 0);
            acc[mt][1] = __builtin_amdgcn_mfma_f32_16x16x32_bf16(afr, bfr1, acc[mt][1], 0, 0, 0);
        }
    }
    __syncthreads();

    // ---- phase 4: epilogue ----
#pragma unroll
    for (int nt = 0; nt < 2; nt++) {
        int colg = n0 + nt * 16 + l16;
        float bb = bl[colg];
#pragma unroll
        for (int mt = 0; mt < 4; mt++)
#pragma unroll
            for (int r = 0; r < 4; r++)
                tl[(mt * 16 + quad * 4 + r) * TLS + colg] = f2bf(acc[mt][nt][r] + bb);
    }
    __syncthreads();

    // ---- phase 5a: coalesced stores (bf16 + fp8 mirror) ----
    for (int i = tid; i < 64 * 64; i += 512) {
        int r = i >> 6, c4 = i & 63;
        int v = m0 + r;
        if (v < N_NODES) {
            ushort4 q = *(ushort4*)(tl + r * TLS + c4 * 4);
            ((ushort4*)hout)[(size_t)v * 64 + c4] = q;
            ((unsigned int*)hout8)[(size_t)v * 64 + c4] =
                pk4fp8(bf2f(q.x), bf2f(q.y), bf2f(q.z), bf2f(q.w));
        }
    }
    // ---- phase 5b: fused readout ----
    {
        int c = tid & 255;
        int r0 = (tid >> 8) * 32;
        float a2 = 0.f;
        int curg = gl[r0];
        for (int r = r0; r < r0 + 32; r++) {
            int gg = gl[r];
            if (gg < 0) break;
            if (gg != curg) {
                atomicAdd(&GsumL[curg * HIDDEN + c], a2);
                a2 = 0.f;
                curg = gg;
            }
            a2 += bf2f(tl[r * TLS + c]);
        }
        if (curg >= 0) atomicAdd(&GsumL[curg * HIDDEN + c], a2);
    }
}

// ====== fused layer (2,3): fp8 gather (vector colu) -> MFMA -> store ========
__global__ __launch_bounds__(512, 8) void k_layer(const unsigned short* __restrict__ h,
                                                  const unsigned char* __restrict__ h8,
                                                  const int* __restrict__ row_ptr,
                                                  const unsigned short* __restrict__ colu,
                                                  const unsigned short* __restrict__ Wpack,
                                                  const float* __restrict__ bias,
                                                  const int* __restrict__ gid,
                                                  unsigned short* __restrict__ hout,
                                                  unsigned char* __restrict__ hout8,
                                                  int wflags,   // bit0: hout, bit1: hout8
                                                  float* __restrict__ GsumL) {
    __shared__ unsigned short tl[64 * TLS];   // 33792 B
    __shared__ int gl[64];
    int tid = threadIdx.x;
    int w = tid >> 6, lane = tid & 63, quad = lane >> 4, l16 = lane & 15;
    int m0 = blockIdx.x * 64;

    // ---- phase 1: fp8 gather + mean; 16B colu vector loads (rows 8-aligned) --
    const unsigned int* h8v = (const unsigned int*)h8;   // 4 fp8 per lane (4 B)
    const ushort4* hv = (const ushort4*)h;
    for (int rr = 0; rr < 8; rr++) {
        int r = w * 8 + rr;
        int v = m0 + r;
        f32x2 A = {0.f, 0.f};   // cols lane*4 + {0,1}
        f32x2 B = {0.f, 0.f};   // cols lane*4 + {2,3}
        if (v < N_NODES) {
            int rp = row_ptr[v];
            int s = rp & 0xffffff;
            int e = s + (int)(((unsigned int)rp) >> 24);
            int i = s;
            for (; i + 8 <= e; i += 8) {
                ushort8v cv = *(const ushort8v*)(colu + i);   // 16B aligned
                unsigned int p0 = h8v[(size_t)cv[0] * 64 + lane];
                unsigned int p1 = h8v[(size_t)cv[1] * 64 + lane];
                unsigned int p2 = h8v[(size_t)cv[2] * 64 + lane];
                unsigned int p3 = h8v[(size_t)cv[3] * 64 + lane];
                unsigned int p4 = h8v[(size_t)cv[4] * 64 + lane];
                unsigned int p5 = h8v[(size_t)cv[5] * 64 + lane];
                unsigned int p6 = h8v[(size_t)cv[6] * 64 + lane];
                unsigned int p7 = h8v[(size_t)cv[7] * 64 + lane];
                A += (pk2f<0>(p0) + pk2f<0>(p1)) + (pk2f<0>(p2) + pk2f<0>(p3))
                   + (pk2f<0>(p4) + pk2f<0>(p5)) + (pk2f<0>(p6) + pk2f<0>(p7));
                B += (pk2f<1>(p0) + pk2f<1>(p1)) + (pk2f<1>(p2) + pk2f<1>(p3))
                   + (pk2f<1>(p4) + pk2f<1>(p5)) + (pk2f<1>(p6) + pk2f<1>(p7));
            }
            if (i + 4 <= e) {
                ushort4 cv = *(const ushort4*)(colu + i);     // 8B aligned
                unsigned int p0 = h8v[(size_t)cv.x * 64 + lane];
                unsigned int p1 = h8v[(size_t)cv.y * 64 + lane];
                unsigned int p2 = h8v[(size_t)cv.z * 64 + lane];
                unsigned int p3 = h8v[(size_t)cv.w * 64 + lane];
                A += (pk2f<0>(p0) + pk2f<0>(p1)) + (pk2f<0>(p2) + pk2f<0>(p3));
                B += (pk2f<1>(p0) + pk2f<1>(p1)) + (pk2f<1>(p2) + pk2f<1>(p3));
                i += 4;
            }
            for (; i < e; i++) {
                unsigned int p = h8v[(size_t)colu[i] * 64 + lane];
                A += pk2f<0>(p);
                B += pk2f<1>(p);
            }
            float inv = (e > s) ? 1.0f / (float)(e - s) : 0.0f;
            ushort4 hs = hv[(size_t)v * 64 + lane];   // self-term bf16
            A.x = bf2f(hs.x) + inv * A.x;
            A.y = bf2f(hs.y) + inv * A.y;
            B.x = bf2f(hs.z) + inv * B.x;
            B.y = bf2f(hs.w) + inv * B.y;
        }
        ushort4 o;
        o.x = f2bf(A.x); o.y = f2bf(A.y); o.z = f2bf(B.x); o.w = f2bf(B.y);
        *(ushort4*)(tl + r * TLS + lane * 4) = o;
    }
    if (tid < 64) gl[tid] = (m0 + tid < N_NODES) ? gid[m0 + tid] : -1;
    __syncthreads();

    // ---- phase 2: MFMA ----
    int n0 = w * 32;
    f32x4 acc[4][2];
#pragma unroll
    for (int mt = 0; mt < 4; mt++) {
        acc[mt][0] = (f32x4){0.f, 0.f, 0.f, 0.f};
        acc[mt][1] = (f32x4){0.f, 0.f, 0.f, 0.f};
    }
#pragma unroll
    for (int ks = 0; ks < 8; ks++) {
        int kg = ks * 4 + quad;
        short8v bfr0 = *(const short8v*)(Wpack + (size_t)(kg * 256 + n0 + l16) * 8);
        short8v bfr1 = *(const short8v*)(Wpack + (size_t)(kg * 256 + n0 + 16 + l16) * 8);
#pragma unroll
        for (int mt = 0; mt < 4; mt++) {
            short8v afr = *(const short8v*)(tl + (mt * 16 + l16) * TLS + ks * 32 + quad * 8);
            acc[mt][0] = __builtin_amdgcn_mfma_f32_16x16x32_bf16(afr, bfr0, acc[mt][0], 0, 0, 0);
            acc[mt][1] = __builtin_amdgcn_mfma_f32_16x16x32_bf16(afr, bfr1, acc[mt][1], 0, 0, 0);
        }
    }
    __syncthreads();

    // ---- phase 3: epilogue ----
#pragma unroll
    for (int nt = 0; nt < 2; nt++) {
        int colg = n0 + nt * 16 + l16;
        float bb = bias[colg];
#pragma unroll
        for (int mt = 0; mt < 4; mt++)
#pragma unroll
            for (int r = 0; r < 4; r++)
                tl[(mt * 16 + quad * 4 + r) * TLS + colg] = f2bf(acc[mt][nt][r] + bb);
    }
    __syncthreads();

    // ---- phase 4a: coalesced stores (flag-gated) ----
    if (wflags) {
        for (int i = tid; i < 64 * 64; i += 512) {
            int r = i >> 6, c4 = i & 63;
            int v = m0 + r;
            if (v < N_NODES) {
                ushort4 q = *(ushort4*)(tl + r * TLS + c4 * 4);
                if (wflags & 1)
                    ((ushort4*)hout)[(size_t)v * 64 + c4] = q;
                if (wflags & 2)
                    ((unsigned int*)hout8)[(size_t)v * 64 + c4] =
                        pk4fp8(bf2f(q.x), bf2f(q.y), bf2f(q.z), bf2f(q.w));
            }
        }
    }
    // ---- phase 4b: fused readout ----
    {
        int c = tid & 255;
        int r0 = (tid >> 8) * 32;
        float a2 = 0.f;
        int curg = gl[r0];
        for (int r = r0; r < r0 + 32; r++) {
            int g = gl[r];
            if (g < 0) break;
            if (g != curg) {
                atomicAdd(&GsumL[curg * HIDDEN + c], a2);
                a2 = 0.f;
                curg = g;
            }
            a2 += bf2f(tl[r * TLS + c]);
        }
        if (curg >= 0) atomicAdd(&GsumL[curg * HIDDEN + c], a2);
    }
}

// ================= out[g] = (concat gmean) @ W_out + b_out ==================
__global__ __launch_bounds__(256) void k_out(const float* __restrict__ Gsum,
                                             const int* __restrict__ gcnt,
                                             const float* __restrict__ Wout,
                                             const float* __restrict__ bout,
                                             float* __restrict__ out) {
    int g = blockIdx.x;
    int c = threadIdx.x;
    __shared__ float gm[HIDDEN * CONV_NUMS];
    float invc = 1.0f / fmaxf((float)gcnt[g], 1.0f);
    for (int i = c; i < HIDDEN * CONV_NUMS; i += 256) {
        int l = i >> 8;
        int k = i & 255;
        gm[i] = Gsum[(size_t)l * N_GRAPHS * HIDDEN + g * HIDDEN + k] * invc;
    }
    __syncthreads();
    float acc = bout[c];
    const float4* gm4 = (const float4*)gm;
    for (int k0 = 0; k0 < HIDDEN * CONV_NUMS; k0 += 4) {
        float4 gv = gm4[k0 >> 2];
        acc += gv.x * Wout[(k0 + 0) * HIDDEN + c];
        acc += gv.y * Wout[(k0 + 1) * HIDDEN + c];
        acc += gv.z * Wout[(k0 + 2) * HIDDEN + c];
        acc += gv.w * Wout[(k0 + 3) * HIDDEN + c];
    }
    out[g * HIDDEN + c] = acc;
}

extern "C" void kernel_launch(void* const* d_in, const int* in_sizes, int n_in,
                              void* d_out, int out_size, void* d_ws, size_t ws_size,
                              hipStream_t stream) {
    const float* X    = (const float*)d_in[0];
    const int*   src  = (const int*)d_in[1];
    const int*   dst  = (const int*)d_in[2];
    const int*   gid  = (const int*)d_in[3];
    const float* Wp   = (const float*)d_in[4];
    const float* bp   = (const float*)d_in[5];
    const float* Wl   = (const float*)d_in[6];
    const float* bl   = (const float*)d_in[7];
    const float* Wout = (const float*)d_in[8];
    const float* bout = (const float*)d_in[9];
    float* out = (float*)d_out;

    char* ws = (char*)d_ws;
    size_t off = 0;
    auto alloc = [&](size_t bytes) {
        char* p = ws + off;
        off += (bytes + 255) & ~size_t(255);
        return p;
    };
    unsigned short* h         = (unsigned short*)alloc(sizeof(short) * N_NODES * HIDDEN);
    unsigned short* t         = (unsigned short*)alloc(sizeof(short) * N_NODES * HIDDEN);
    unsigned char*  h8a       = (unsigned char*)alloc((size_t)N_NODES * HIDDEN);
    unsigned char*  h8b       = (unsigned char*)alloc((size_t)N_NODES * HIDDEN);
    unsigned short* WlPack    = (unsigned short*)alloc(sizeof(short) * HIDDEN * HIDDEN);
    unsigned short* WprojPack = (unsigned short*)alloc(sizeof(short) * 8 * 256 * 8);
    unsigned short* Xb        = (unsigned short*)alloc(sizeof(short) * N_NODES * XK);
    unsigned char*  Xb8p      = (unsigned char*)alloc((size_t)N_NODES * XK8);
    int*   pairs   = (int*)alloc(sizeof(int) * NBK * CAP);
    unsigned short* colu = (unsigned short*)alloc(sizeof(short) * NBK * CAP);
    int*   row_ptr = (int*)alloc(sizeof(int) * (N_NODES + 1));
    int*   bucket_cursor = (int*)alloc(sizeof(int) * NBK);
    // contiguous zero region: gcnt | Gsum -> one memset
    char*  zero0 = ws + off;
    int*   gcnt = (int*)alloc(sizeof(int) * N_GRAPHS);
    float* Gsum = (float*)alloc(sizeof(float) * CONV_NUMS * N_GRAPHS * HIDDEN);
    size_t zero_bytes = (size_t)((char*)(Gsum + CONV_NUMS * N_GRAPHS * HIDDEN) - zero0);

    hipMemsetAsync(zero0, 0, zero_bytes, stream);

    {
        const int TOT8 = N_NODES * XK8;
        int ncast = (TOT8 + 2047) / 2048;
        k_build0<<<104 + ncast, 256, 0, stream>>>(gid, Wl, Wp, X, bucket_cursor,
                                                  gcnt, WlPack, WprojPack, Xb, Xb8p);
    }
    k_passB<<<(N_EDGES + BCH - 1) / BCH, 256, 0, stream>>>(src, dst, bucket_cursor, pairs);
    k_passC<<<NBK, 256, 0, stream>>>(pairs, bucket_cursor, row_ptr, colu);

    // layer 1 (fused proj + conv1 + readout); writes bf16 h + fp8 mirror h8a
    k_layer1<<<(N_NODES + 63) / 64, 512, 0, stream>>>(
        Xb, Xb8p, row_ptr, colu, WprojPack, bp, WlPack, bl, gid, h, h8a, Gsum);

    // layer 2: gather fp8(h8a), self bf16 h -> t + h8b
    k_layer<<<(N_NODES + 63) / 64, 512, 0, stream>>>(
        h, h8a, row_ptr, colu, WlPack, bl, gid, t, h8b, 3,
        Gsum + (size_t)1 * N_GRAPHS * HIDDEN);

    // layer 3: gather fp8(h8b), self bf16 t -> readout only (no stores)
    k_layer<<<(N_NODES + 63) / 64, 512, 0, stream>>>(
        t, h8b, row_ptr, colu, WlPack, bl, gid, h, h8a, 0,
        Gsum + (size_t)2 * N_GRAPHS * HIDDEN);

    k_out<<<N_GRAPHS, 256, 0, stream>>>(Gsum, gcnt, Wout, bout, out);
}

// Round 16
// 336.016 us; speedup vs baseline: 1.5568x; 1.0048x over previous
//
#include <hip/hip_runtime.h>
#include <hip/hip_fp8.h>

#define N_NODES   50000
#define N_EDGES   1600000
#define N_GRAPHS  512
#define IN_SIZE   44
#define HIDDEN    256
#define CONV_NUMS 3
#define NBK       ((N_NODES + 255) / 256)   // 196 dst-buckets of 256 nodes
#define CAP       16384                     // fixed colu/pairs stride per bucket
#define XK        48                        // bf16 X row stride (self-term)
#define XK8       64                        // fp8 X row stride (gather table, padded)

typedef __attribute__((ext_vector_type(8))) short short8v;            // 8 bf16 = 16 B
typedef __attribute__((ext_vector_type(8))) unsigned short ushort8v;  // 8 u16 = 16 B
typedef __attribute__((ext_vector_type(4))) float f32x4;              // MFMA C/D frag
typedef __attribute__((ext_vector_type(2))) float f32x2;

__device__ __forceinline__ float bf2f(unsigned short u) {
    return __uint_as_float(((unsigned int)u) << 16);
}
__device__ __forceinline__ unsigned short f2bf(float f) {
    unsigned int u = __float_as_uint(f);
    unsigned int r = (u + 0x7fffu + ((u >> 16) & 1u)) >> 16;  // RNE
    return (unsigned short)r;
}

// ---- fp8 e4m3 (OCP on gfx950) helpers: HW cvt with HIP-type fallback ----
#if __has_builtin(__builtin_amdgcn_cvt_f32_fp8)
template <int SEL>
__device__ __forceinline__ float fp8tof(unsigned int w) {
    return __builtin_amdgcn_cvt_f32_fp8((int)w, SEL);
}
#else
template <int SEL>
__device__ __forceinline__ float fp8tof(unsigned int w) {
    __hip_fp8_e4m3 q;
    q.__x = (__hip_fp8_storage_t)((w >> (SEL * 8)) & 0xff);
    return (float)q;
}
#endif

#if __has_builtin(__builtin_amdgcn_cvt_pk_f32_fp8)
template <int HI>
__device__ __forceinline__ f32x2 pk2f(unsigned int w) {
    return __builtin_amdgcn_cvt_pk_f32_fp8((int)w, HI != 0);
}
#else
template <int HI>
__device__ __forceinline__ f32x2 pk2f(unsigned int w) {
    f32x2 r;
    r.x = fp8tof<2 * HI>(w);
    r.y = fp8tof<2 * HI + 1>(w);
    return r;
}
#endif

#if __has_builtin(__builtin_amdgcn_cvt_pk_fp8_f32)
__device__ __forceinline__ unsigned int pk4fp8(float f0, float f1, float f2, float f3) {
    int lo = __builtin_amdgcn_cvt_pk_fp8_f32(f0, f1, 0, false);
    return (unsigned int)__builtin_amdgcn_cvt_pk_fp8_f32(f2, f3, lo, true);
}
#else
__device__ __forceinline__ unsigned int pk4fp8(float f0, float f1, float f2, float f3) {
    __hip_fp8_e4m3 a(f0), b(f1), c(f2), d(f3);
    return (unsigned int)a.__x | ((unsigned int)b.__x << 8) |
           ((unsigned int)c.__x << 16) | ((unsigned int)d.__x << 24);
}
#endif

__device__ __forceinline__ unsigned char f2fp8(float f) {
    return (unsigned char)(pk4fp8(f, 0.f, 0.f, 0.f) & 0xff);
}

// ========= fused: graph histogram + cursor init + weight pack + X cast ======
// blocks [0,64): gcnt histogram (+ block 0 inits bucket_cursor[b]=b*CAP);
// [64,96): WlPack; [96,104): WprojPack; [104, 104+ncast): Xb/Xb8p cast.
__global__ __launch_bounds__(256) void k_build0(const int* __restrict__ gid,
                                                const float* __restrict__ Wl,
                                                const float* __restrict__ Wproj,
                                                const float* __restrict__ X,
                                                int* __restrict__ bucket_cursor,
                                                int* __restrict__ gcnt,
                                                unsigned short* __restrict__ WlPack,
                                                unsigned short* __restrict__ WprojPack,
                                                unsigned short* __restrict__ Xb,
                                                unsigned char* __restrict__ Xb8p) {
    int b = blockIdx.x;
    int tid = threadIdx.x;
    if (b < 64) {
        if (b == 0 && tid < NBK) bucket_cursor[tid] = tid * CAP;
        __shared__ int hg[N_GRAPHS];
        for (int i = tid; i < N_GRAPHS; i += 256) hg[i] = 0;
        __syncthreads();
        int t = b * 256 + tid;
        int stride = 64 * 256;
        for (int v = t; v < N_NODES; v += stride) atomicAdd(&hg[gid[v]], 1);
        __syncthreads();
        for (int i = tid; i < N_GRAPHS; i += 256) if (hg[i]) atomicAdd(&gcnt[i], hg[i]);
    } else if (b < 96) {                // WlPack: 8192 frags
        int i = (b - 64) * 256 + tid;
        int kg = i >> 8, n = i & 255;
        short8v v;
#pragma unroll
        for (int j = 0; j < 8; j++) v[j] = (short)f2bf(Wl[(kg * 8 + j) * HIDDEN + n]);
        *(short8v*)(WlPack + (size_t)(kg * 256 + n) * 8) = v;
    } else if (b < 104) {               // WprojPack: kg in [0,8), zero-pad k>=44
        int i = (b - 96) * 256 + tid;
        int kg = i >> 8, n = i & 255;
        short8v v;
#pragma unroll
        for (int j = 0; j < 8; j++) {
            int k = kg * 8 + j;
            v[j] = (k < IN_SIZE) ? (short)f2bf(Wproj[k * HIDDEN + n]) : (short)0;
        }
        *(short8v*)(WprojPack + (size_t)(kg * 256 + n) * 8) = v;
    } else {                            // Xb8p: N x 64 fp8 (+ Xb: N x 48 bf16)
        const int TOT8 = N_NODES * XK8;
        int id0 = (b - 104) * 2048 + tid;
#pragma unroll
        for (int j = 0; j < 8; j++) {
            int id = id0 + j * 256;
            if (id < TOT8) {
                int row = id >> 6, c = id & 63;
                float val = (c < IN_SIZE) ? X[row * IN_SIZE + c] : 0.f;
                Xb8p[id] = f2fp8(val);
                if (c < XK) Xb[(size_t)row * XK + c] = f2bf(val);
            }
        }
    }
}

// Pass B: LDS-sort 8192-edge chunks by bucket; write packed (b,ldst,src) runs
// into fixed-stride bucket regions of `pairs` via bucket_cursor reservations.
#define BCH 8192
__global__ __launch_bounds__(256) void k_passB(const int* __restrict__ src,
                                               const int* __restrict__ dst,
                                               int* __restrict__ bucket_cursor,
                                               int* __restrict__ pairs) {
    __shared__ int hist[NBK];
    __shared__ int excl[NBK];
    __shared__ int cur[NBK];
    __shared__ int gbase[NBK];
    __shared__ int lp[BCH];
    __shared__ int sc[256];
    int tid = threadIdx.x;
    int e0 = blockIdx.x * BCH;
    int cnt = min(BCH, N_EDGES - e0);
    for (int i = tid; i < NBK; i += 256) hist[i] = 0;
    __syncthreads();
    for (int i = tid; i < cnt; i += 256) atomicAdd(&hist[dst[e0 + i] >> 8], 1);
    __syncthreads();
    int hv = (tid < NBK) ? hist[tid] : 0;
    sc[tid] = hv;
    __syncthreads();
    for (int off = 1; off < 256; off <<= 1) {
        int a = (tid >= off) ? sc[tid - off] : 0;
        __syncthreads();
        sc[tid] += a;
        __syncthreads();
    }
    if (tid < NBK) {
        excl[tid] = sc[tid] - hv;
        cur[tid]  = sc[tid] - hv;
    }
    __syncthreads();
    for (int i = tid; i < cnt; i += 256) {
        int d = dst[e0 + i];
        int b = d >> 8;
        int pos = atomicAdd(&cur[b], 1);
        lp[pos] = (b << 24) | ((d & 255) << 16) | src[e0 + i];
    }
    __syncthreads();
    if (tid < NBK && hist[tid] > 0)
        gbase[tid] = atomicAdd(&bucket_cursor[tid], hist[tid]);
    __syncthreads();
    for (int i = tid; i < cnt; i += 256) {
        int p = lp[i];
        int b = (p >> 24) & 0xff;
        pairs[gbase[b] + (i - excl[b])] = p;
    }
}

// Pass C: one block per bucket -> packed row_ptr (start | deg<<24) + colu.
// Row starts padded to multiples of 8 entries (16 B-aligned ushort8 loads).
__global__ __launch_bounds__(256) void k_passC(const int* __restrict__ pairs,
                                               const int* __restrict__ bucket_cursor,
                                               int* __restrict__ row_ptr,
                                               unsigned short* __restrict__ colu) {
    __shared__ int hist[256];
    __shared__ int cur[256];
    __shared__ int sc[256];
    int b = blockIdx.x;
    int tid = threadIdx.x;
    int v0 = b << 8;
    int e0 = b * CAP;
    int e1 = bucket_cursor[b];          // base + count after passB
    hist[tid] = 0;
    __syncthreads();
    for (int i = e0 + tid; i < e1; i += 256) atomicAdd(&hist[(pairs[i] >> 16) & 0xff], 1);
    __syncthreads();
    int hv = hist[tid];
    int hv8 = (hv + 7) & ~7;            // 8-aligned row span
    sc[tid] = hv8;
    __syncthreads();
    for (int off = 1; off < 256; off <<= 1) {
        int a = (tid >= off) ? sc[tid - off] : 0;
        __syncthreads();
        sc[tid] += a;
        __syncthreads();
    }
    int base = e0 + sc[tid] - hv8;
    int v = v0 + tid;
    if (v < N_NODES) row_ptr[v] = base | (hv << 24);
    cur[tid] = base;
    __syncthreads();
    for (int i = e0 + tid; i < e1; i += 256) {
        int p = pairs[i];
        int pos = atomicAdd(&cur[(p >> 16) & 0xff], 1);
        colu[pos] = (unsigned short)(p & 0xffff);
    }
}

// ====== fused layer 1: 4-edge-batched fp8-X gather -> 2x MFMA -> store ======
#define TLS 264
#define K1S 72
__global__ __launch_bounds__(512, 8) void k_layer1(const unsigned short* __restrict__ Xb,
                                                   const unsigned char* __restrict__ Xb8p,
                                                   const int* __restrict__ row_ptr,
                                                   const unsigned short* __restrict__ colu,
                                                   const unsigned short* __restrict__ WprojPack,
                                                   const float* __restrict__ bp,
                                                   const unsigned short* __restrict__ WlPack,
                                                   const float* __restrict__ bl,
                                                   const int* __restrict__ gid,
                                                   unsigned short* __restrict__ hout,
                                                   unsigned char* __restrict__ hout8,
                                                   float* __restrict__ GsumL) {
    __shared__ unsigned short tl[64 * TLS];
    unsigned short* tl1 = tl;          // overlay: 64*K1S = 4608 shorts
    float* redbase = (float*)(tl + 64 * K1S);   // dead zone of tl in phase 1
    __shared__ float bpm[64];
    __shared__ int gl[64];
    int tid = threadIdx.x;
    int w = tid >> 6, lane = tid & 63, quad = lane >> 4, l16 = lane & 15;
    int g = lane >> 4, sub = lane & 15;
    int m0 = blockIdx.x * 64;
    float* red = redbase + w * 256;

    // ---- phase 1: batched fp8 gather of X rows (4 edges per load) ----
    const unsigned int* X8 = (const unsigned int*)Xb8p;   // row stride 16 uints
    for (int rr = 0; rr < 8; rr++) {
        int r = w * 8 + rr;
        int v = m0 + r;
        f32x2 A = {0.f, 0.f};
        f32x2 Bv = {0.f, 0.f};
        int s = 0, e = 0;
        if (v < N_NODES) {
            int rp = row_ptr[v];
            s = rp & 0xffffff;
            e = s + (int)(((unsigned int)rp) >> 24);
        }
        int i = s;
        for (; i + 8 <= e; i += 8) {
            int ua = colu[i + g];
            int ub = colu[i + 4 + g];
            unsigned int pa = X8[ua * 16 + sub];
            unsigned int pb = X8[ub * 16 + sub];
            A  += pk2f<0>(pa) + pk2f<0>(pb);
            Bv += pk2f<1>(pa) + pk2f<1>(pb);
        }
        if (i + 4 <= e) {
            int ua = colu[i + g];
            unsigned int pa = X8[ua * 16 + sub];
            A += pk2f<0>(pa);
            Bv += pk2f<1>(pa);
            i += 4;
        }
        if (i < e) {   // wave-uniform guard; branchless per-lane tail
            int idx = i + g;
            int cl = (idx < e) ? idx : (e - 1);
            int ua = colu[cl];
            unsigned int pa = X8[ua * 16 + sub];
            float mvalid = (idx < e) ? 1.f : 0.f;
            f32x2 za = pk2f<0>(pa), zb = pk2f<1>(pa);
            A.x += mvalid * za.x; A.y += mvalid * za.y;
            Bv.x += mvalid * zb.x; Bv.y += mvalid * zb.y;
        }
        *(f32x4*)(red + g * 64 + sub * 4) = (f32x4){A.x, A.y, Bv.x, Bv.y};
        float ssum = (red[0 * 64 + lane] + red[1 * 64 + lane])
                   + (red[2 * 64 + lane] + red[3 * 64 + lane]);
        float val = 0.f;
        float mul = 1.f;
        if (v < N_NODES) {
            float inv = 0.f;
            if (e > s) { inv = 1.0f / (float)(e - s); mul = 2.f; }
            float self = (lane < XK) ? bf2f(Xb[(size_t)v * XK + lane]) : 0.f;
            val = self + inv * ssum;
        }
        tl1[r * K1S + lane] = (lane < XK) ? f2bf(val) : (unsigned short)0;
        if (lane == 0) bpm[r] = mul;
    }
    if (tid < 64) gl[tid] = (m0 + tid < N_NODES) ? gid[m0 + tid] : -1;
    __syncthreads();

    // ---- phase 2: MFMA stage 1 (A = tl1 64x64, B = WprojPack) ----
    int n0 = w * 32;
    f32x4 acc[4][2];
#pragma unroll
    for (int mt = 0; mt < 4; mt++) {
        acc[mt][0] = (f32x4){0.f, 0.f, 0.f, 0.f};
        acc[mt][1] = (f32x4){0.f, 0.f, 0.f, 0.f};
    }
#pragma unroll
    for (int ks = 0; ks < 2; ks++) {
        int kg = ks * 4 + quad;
        short8v bfr0 = *(const short8v*)(WprojPack + (size_t)(kg * 256 + n0 + l16) * 8);
        short8v bfr1 = *(const short8v*)(WprojPack + (size_t)(kg * 256 + n0 + 16 + l16) * 8);
#pragma unroll
        for (int mt = 0; mt < 4; mt++) {
            short8v afr = *(const short8v*)(tl1 + (mt * 16 + l16) * K1S + ks * 32 + quad * 8);
            acc[mt][0] = __builtin_amdgcn_mfma_f32_16x16x32_bf16(afr, bfr0, acc[mt][0], 0, 0, 0);
            acc[mt][1] = __builtin_amdgcn_mfma_f32_16x16x32_bf16(afr, bfr1, acc[mt][1], 0, 0, 0);
        }
    }
    __syncthreads();   // all tl1 reads complete before tl writes (overlay!)
#pragma unroll
    for (int nt = 0; nt < 2; nt++) {
        int colg = n0 + nt * 16 + l16;
        float bb = bp[colg];
#pragma unroll
        for (int mt = 0; mt < 4; mt++)
#pragma unroll
            for (int r = 0; r < 4; r++) {
                int row = mt * 16 + quad * 4 + r;
                tl[row * TLS + colg] = f2bf(acc[mt][nt][r] + bb * bpm[row]);
            }
    }
    __syncthreads();

    // ---- phase 3: MFMA stage 2 (A = tl 64x256, B = WlPack) ----
#pragma unroll
    for (int mt = 0; mt < 4; mt++) {
        acc[mt][0] = (f32x4){0.f, 0.f, 0.f, 0.f};
        acc[mt][1] = (f32x4){0.f, 0.f, 0.f, 0.f};
    }
#pragma unroll
    for (int ks = 0; ks < 8; ks++) {
        int kg = ks * 4 + quad;
        short8v bfr0 = *(const short8v*)(WlPack + (size_t)(kg * 256 + n0 + l16) * 8);
        short8v bfr1 = *(const short8v*)(WlPack + (size_t)(kg * 256 + n0 + 16 + l16) * 8);
#pragma unroll
        for (int mt = 0; mt < 4; mt++) {
            short8v afr = *(const short8v*)(tl + (mt * 16 + l16) * TLS + ks * 32 + quad * 8);
            acc[mt][0] = __builtin_amdgcn_mfma_f32_16x16x32_bf16(afr, bfr0, acc[mt][0], 0, 0, 0);
            acc[mt][1] = __builtin_amdgcn_mfma_f32_16x16x32_bf16(afr, bfr1, acc[mt][1], 0, 0, 0);
        }
    }
    __syncthreads();

    // ---- phase 4: epilogue ----
#pragma unroll
    for (int nt = 0; nt < 2; nt++) {
        int colg = n0 + nt * 16 + l16;
        float bb = bl[colg];
#pragma unroll
        for (int mt = 0; mt < 4; mt++)
#pragma unroll
            for (int r = 0; r < 4; r++)
                tl[(mt * 16 + quad * 4 + r) * TLS + colg] = f2bf(acc[mt][nt][r] + bb);
    }
    __syncthreads();

    // ---- phase 5a: coalesced stores (bf16 + fp8 mirror) ----
    for (int i = tid; i < 64 * 64; i += 512) {
        int r = i >> 6, c4 = i & 63;
        int v = m0 + r;
        if (v < N_NODES) {
            ushort4 q = *(ushort4*)(tl + r * TLS + c4 * 4);
            ((ushort4*)hout)[(size_t)v * 64 + c4] = q;
            ((unsigned int*)hout8)[(size_t)v * 64 + c4] =
                pk4fp8(bf2f(q.x), bf2f(q.y), bf2f(q.z), bf2f(q.w));
        }
    }
    // ---- phase 5b: fused readout ----
    {
        int c = tid & 255;
        int r0 = (tid >> 8) * 32;
        float a2 = 0.f;
        int curg = gl[r0];
        for (int r = r0; r < r0 + 32; r++) {
            int gg = gl[r];
            if (gg < 0) break;
            if (gg != curg) {
                atomicAdd(&GsumL[curg * HIDDEN + c], a2);
                a2 = 0.f;
                curg = gg;
            }
            a2 += bf2f(tl[r * TLS + c]);
        }
        if (curg >= 0) atomicAdd(&GsumL[curg * HIDDEN + c], a2);
    }
}

// ====== fused layer (2,3): fp8 gather (16 loads in flight) -> MFMA ==========
__global__ __launch_bounds__(512, 8) void k_layer(const unsigned short* __restrict__ h,
                                                  const unsigned char* __restrict__ h8,
                                                  const int* __restrict__ row_ptr,
                                                  const unsigned short* __restrict__ colu,
                                                  const unsigned short* __restrict__ Wpack,
                                                  const float* __restrict__ bias,
                                                  const int* __restrict__ gid,
                                                  unsigned short* __restrict__ hout,
                                                  unsigned char* __restrict__ hout8,
                                                  int wflags,   // bit0: hout, bit1: hout8
                                                  float* __restrict__ GsumL) {
    __shared__ unsigned short tl[64 * TLS];   // 33792 B
    __shared__ int gl[64];
    int tid = threadIdx.x;
    int w = tid >> 6, lane = tid & 63, quad = lane >> 4, l16 = lane & 15;
    int m0 = blockIdx.x * 64;

    // ---- phase 1: fp8 gather + mean; 16 loads in flight; 16B colu loads ----
    const unsigned int* h8v = (const unsigned int*)h8;   // 4 fp8 per lane (4 B)
    const ushort4* hv = (const ushort4*)h;
    for (int rr = 0; rr < 8; rr++) {
        int r = w * 8 + rr;
        int v = m0 + r;
        f32x2 A = {0.f, 0.f};   // cols lane*4 + {0,1}
        f32x2 B = {0.f, 0.f};   // cols lane*4 + {2,3}
        if (v < N_NODES) {
            int rp = row_ptr[v];
            int s = rp & 0xffffff;
            int e = s + (int)(((unsigned int)rp) >> 24);
            int i = s;
            for (; i + 16 <= e; i += 16) {
                ushort8v ca = *(const ushort8v*)(colu + i);       // 16B aligned
                ushort8v cb = *(const ushort8v*)(colu + i + 8);
                unsigned int p0 = h8v[(size_t)ca[0] * 64 + lane];
                unsigned int p1 = h8v[(size_t)ca[1] * 64 + lane];
                unsigned int p2 = h8v[(size_t)ca[2] * 64 + lane];
                unsigned int p3 = h8v[(size_t)ca[3] * 64 + lane];
                unsigned int p4 = h8v[(size_t)ca[4] * 64 + lane];
                unsigned int p5 = h8v[(size_t)ca[5] * 64 + lane];
                unsigned int p6 = h8v[(size_t)ca[6] * 64 + lane];
                unsigned int p7 = h8v[(size_t)ca[7] * 64 + lane];
                unsigned int q0 = h8v[(size_t)cb[0] * 64 + lane];
                unsigned int q1 = h8v[(size_t)cb[1] * 64 + lane];
                unsigned int q2 = h8v[(size_t)cb[2] * 64 + lane];
                unsigned int q3 = h8v[(size_t)cb[3] * 64 + lane];
                unsigned int q4 = h8v[(size_t)cb[4] * 64 + lane];
                unsigned int q5 = h8v[(size_t)cb[5] * 64 + lane];
                unsigned int q6 = h8v[(size_t)cb[6] * 64 + lane];
                unsigned int q7 = h8v[(size_t)cb[7] * 64 + lane];
                A += ((pk2f<0>(p0) + pk2f<0>(p1)) + (pk2f<0>(p2) + pk2f<0>(p3)))
                   + ((pk2f<0>(p4) + pk2f<0>(p5)) + (pk2f<0>(p6) + pk2f<0>(p7)))
                   + ((pk2f<0>(q0) + pk2f<0>(q1)) + (pk2f<0>(q2) + pk2f<0>(q3)))
                   + ((pk2f<0>(q4) + pk2f<0>(q5)) + (pk2f<0>(q6) + pk2f<0>(q7)));
                B += ((pk2f<1>(p0) + pk2f<1>(p1)) + (pk2f<1>(p2) + pk2f<1>(p3)))
                   + ((pk2f<1>(p4) + pk2f<1>(p5)) + (pk2f<1>(p6) + pk2f<1>(p7)))
                   + ((pk2f<1>(q0) + pk2f<1>(q1)) + (pk2f<1>(q2) + pk2f<1>(q3)))
                   + ((pk2f<1>(q4) + pk2f<1>(q5)) + (pk2f<1>(q6) + pk2f<1>(q7)));
            }
            if (i + 8 <= e) {
                ushort8v cv = *(const ushort8v*)(colu + i);
                unsigned int p0 = h8v[(size_t)cv[0] * 64 + lane];
                unsigned int p1 = h8v[(size_t)cv[1] * 64 + lane];
                unsigned int p2 = h8v[(size_t)cv[2] * 64 + lane];
                unsigned int p3 = h8v[(size_t)cv[3] * 64 + lane];
                unsigned int p4 = h8v[(size_t)cv[4] * 64 + lane];
                unsigned int p5 = h8v[(size_t)cv[5] * 64 + lane];
                unsigned int p6 = h8v[(size_t)cv[6] * 64 + lane];
                unsigned int p7 = h8v[(size_t)cv[7] * 64 + lane];
                A += (pk2f<0>(p0) + pk2f<0>(p1)) + (pk2f<0>(p2) + pk2f<0>(p3))
                   + (pk2f<0>(p4) + pk2f<0>(p5)) + (pk2f<0>(p6) + pk2f<0>(p7));
                B += (pk2f<1>(p0) + pk2f<1>(p1)) + (pk2f<1>(p2) + pk2f<1>(p3))
                   + (pk2f<1>(p4) + pk2f<1>(p5)) + (pk2f<1>(p6) + pk2f<1>(p7));
                i += 8;
            }
            if (i + 4 <= e) {
                ushort4 cv = *(const ushort4*)(colu + i);     // 8B aligned
                unsigned int p0 = h8v[(size_t)cv.x * 64 + lane];
                unsigned int p1 = h8v[(size_t)cv.y * 64 + lane];
                unsigned int p2 = h8v[(size_t)cv.z * 64 + lane];
                unsigned int p3 = h8v[(size_t)cv.w * 64 + lane];
                A += (pk2f<0>(p0) + pk2f<0>(p1)) + (pk2f<0>(p2) + pk2f<0>(p3));
                B += (pk2f<1>(p0) + pk2f<1>(p1)) + (pk2f<1>(p2) + pk2f<1>(p3));
                i += 4;
            }
            for (; i < e; i++) {
                unsigned int p = h8v[(size_t)colu[i] * 64 + lane];
                A += pk2f<0>(p);
                B += pk2f<1>(p);
            }
            float inv = (e > s) ? 1.0f / (float)(e - s) : 0.0f;
            ushort4 hs = hv[(size_t)v * 64 + lane];   // self-term bf16
            A.x = bf2f(hs.x) + inv * A.x;
            A.y = bf2f(hs.y) + inv * A.y;
            B.x = bf2f(hs.z) + inv * B.x;
            B.y = bf2f(hs.w) + inv * B.y;
        }
        ushort4 o;
        o.x = f2bf(A.x); o.y = f2bf(A.y); o.z = f2bf(B.x); o.w = f2bf(B.y);
        *(ushort4*)(tl + r * TLS + lane * 4) = o;
    }
    if (tid < 64) gl[tid] = (m0 + tid < N_NODES) ? gid[m0 + tid] : -1;
    __syncthreads();

    // ---- phase 2: MFMA ----
    int n0 = w * 32;
    f32x4 acc[4][2];
#pragma unroll
    for (int mt = 0; mt < 4; mt++) {
        acc[mt][0] = (f32x4){0.f, 0.f, 0.f, 0.f};
        acc[mt][1] = (f32x4){0.f, 0.f, 0.f, 0.f};
    }
#pragma unroll
    for (int ks = 0; ks < 8; ks++) {
        int kg = ks * 4 + quad;
        short8v bfr0 = *(const short8v*)(Wpack + (size_t)(kg * 256 + n0 + l16) * 8);
        short8v bfr1 = *(const short8v*)(Wpack + (size_t)(kg * 256 + n0 + 16 + l16) * 8);
#pragma unroll
        for (int mt = 0; mt < 4; mt++) {
            short8v afr = *(const short8v*)(tl + (mt * 16 + l16) * TLS + ks * 32 + quad * 8);
            acc[mt][0] = __builtin_amdgcn_mfma_f32_16x16x32_bf16(afr, bfr0, acc[mt][0], 0, 0, 0);
            acc[mt][1] = __builtin_amdgcn_mfma_f32_16x16x32_bf16(afr, bfr1, acc[mt][1], 0, 0, 0);
        }
    }
    __syncthreads();

    // ---- phase 3: epilogue ----
#pragma unroll
    for (int nt = 0; nt < 2; nt++) {
        int colg = n0 + nt * 16 + l16;
        float bb = bias[colg];
#pragma unroll
        for (int mt = 0; mt < 4; mt++)
#pragma unroll
            for (int r = 0; r < 4; r++)
                tl[(mt * 16 + quad * 4 + r) * TLS + colg] = f2bf(acc[mt][nt][r] + bb);
    }
    __syncthreads();

    // ---- phase 4a: coalesced stores (flag-gated) ----
    if (wflags) {
        for (int i = tid; i < 64 * 64; i += 512) {
            int r = i >> 6, c4 = i & 63;
            int v = m0 + r;
            if (v < N_NODES) {
                ushort4 q = *(ushort4*)(tl + r * TLS + c4 * 4);
                if (wflags & 1)
                    ((ushort4*)hout)[(size_t)v * 64 + c4] = q;
                if (wflags & 2)
                    ((unsigned int*)hout8)[(size_t)v * 64 + c4] =
                        pk4fp8(bf2f(q.x), bf2f(q.y), bf2f(q.z), bf2f(q.w));
            }
        }
    }
    // ---- phase 4b: fused readout ----
    {
        int c = tid & 255;
        int r0 = (tid >> 8) * 32;
        float a2 = 0.f;
        int curg = gl[r0];
        for (int r = r0; r < r0 + 32; r++) {
            int g = gl[r];
            if (g < 0) break;
            if (g != curg) {
                atomicAdd(&GsumL[curg * HIDDEN + c], a2);
                a2 = 0.f;
                curg = g;
            }
            a2 += bf2f(tl[r * TLS + c]);
        }
        if (curg >= 0) atomicAdd(&GsumL[curg * HIDDEN + c], a2);
    }
}

// ================= out[g] = (concat gmean) @ W_out + b_out ==================
__global__ __launch_bounds__(256) void k_out(const float* __restrict__ Gsum,
                                             const int* __restrict__ gcnt,
                                             const float* __restrict__ Wout,
                                             const float* __restrict__ bout,
                                             float* __restrict__ out) {
    int g = blockIdx.x;
    int c = threadIdx.x;
    __shared__ float gm[HIDDEN * CONV_NUMS];
    float invc = 1.0f / fmaxf((float)gcnt[g], 1.0f);
    for (int i = c; i < HIDDEN * CONV_NUMS; i += 256) {
        int l = i >> 8;
        int k = i & 255;
        gm[i] = Gsum[(size_t)l * N_GRAPHS * HIDDEN + g * HIDDEN + k] * invc;
    }
    __syncthreads();
    float acc = bout[c];
    const float4* gm4 = (const float4*)gm;
    for (int k0 = 0; k0 < HIDDEN * CONV_NUMS; k0 += 4) {
        float4 gv = gm4[k0 >> 2];
        acc += gv.x * Wout[(k0 + 0) * HIDDEN + c];
        acc += gv.y * Wout[(k0 + 1) * HIDDEN + c];
        acc += gv.z * Wout[(k0 + 2) * HIDDEN + c];
        acc += gv.w * Wout[(k0 + 3) * HIDDEN + c];
    }
    out[g * HIDDEN + c] = acc;
}

extern "C" void kernel_launch(void* const* d_in, const int* in_sizes, int n_in,
                              void* d_out, int out_size, void* d_ws, size_t ws_size,
                              hipStream_t stream) {
    const float* X    = (const float*)d_in[0];
    const int*   src  = (const int*)d_in[1];
    const int*   dst  = (const int*)d_in[2];
    const int*   gid  = (const int*)d_in[3];
    const float* Wp   = (const float*)d_in[4];
    const float* bp   = (const float*)d_in[5];
    const float* Wl   = (const float*)d_in[6];
    const float* bl   = (const float*)d_in[7];
    const float* Wout = (const float*)d_in[8];
    const float* bout = (const float*)d_in[9];
    float* out = (float*)d_out;

    char* ws = (char*)d_ws;
    size_t off = 0;
    auto alloc = [&](size_t bytes) {
        char* p = ws + off;
        off += (bytes + 255) & ~size_t(255);
        return p;
    };
    unsigned short* h         = (unsigned short*)alloc(sizeof(short) * N_NODES * HIDDEN);
    unsigned short* t         = (unsigned short*)alloc(sizeof(short) * N_NODES * HIDDEN);
    unsigned char*  h8a       = (unsigned char*)alloc((size_t)N_NODES * HIDDEN);
    unsigned char*  h8b       = (unsigned char*)alloc((size_t)N_NODES * HIDDEN);
    unsigned short* WlPack    = (unsigned short*)alloc(sizeof(short) * HIDDEN * HIDDEN);
    unsigned short* WprojPack = (unsigned short*)alloc(sizeof(short) * 8 * 256 * 8);
    unsigned short* Xb        = (unsigned short*)alloc(sizeof(short) * N_NODES * XK);
    unsigned char*  Xb8p      = (unsigned char*)alloc((size_t)N_NODES * XK8);
    int*   pairs   = (int*)alloc(sizeof(int) * NBK * CAP);
    unsigned short* colu = (unsigned short*)alloc(sizeof(short) * NBK * CAP);
    int*   row_ptr = (int*)alloc(sizeof(int) * (N_NODES + 1));
    int*   bucket_cursor = (int*)alloc(sizeof(int) * NBK);
    // contiguous zero region: gcnt | Gsum -> one memset
    char*  zero0 = ws + off;
    int*   gcnt = (int*)alloc(sizeof(int) * N_GRAPHS);
    float* Gsum = (float*)alloc(sizeof(float) * CONV_NUMS * N_GRAPHS * HIDDEN);
    size_t zero_bytes = (size_t)((char*)(Gsum + CONV_NUMS * N_GRAPHS * HIDDEN) - zero0);

    hipMemsetAsync(zero0, 0, zero_bytes, stream);

    {
        const int TOT8 = N_NODES * XK8;
        int ncast = (TOT8 + 2047) / 2048;
        k_build0<<<104 + ncast, 256, 0, stream>>>(gid, Wl, Wp, X, bucket_cursor,
                                                  gcnt, WlPack, WprojPack, Xb, Xb8p);
    }
    k_passB<<<(N_EDGES + BCH - 1) / BCH, 256, 0, stream>>>(src, dst, bucket_cursor, pairs);
    k_passC<<<NBK, 256, 0, stream>>>(pairs, bucket_cursor, row_ptr, colu);

    // layer 1 (fused proj + conv1 + readout); writes bf16 h + fp8 mirror h8a
    k_layer1<<<(N_NODES + 63) / 64, 512, 0, stream>>>(
        Xb, Xb8p, row_ptr, colu, WprojPack, bp, WlPack, bl, gid, h, h8a, Gsum);

    // layer 2: gather fp8(h8a), self bf16 h -> t + h8b
    k_layer<<<(N_NODES + 63) / 64, 512, 0, stream>>>(
        h, h8a, row_ptr, colu, WlPack, bl, gid, t, h8b, 3,
        Gsum + (size_t)1 * N_GRAPHS * HIDDEN);

    // layer 3: gather fp8(h8b), self bf16 t -> readout only (no stores)
    k_layer<<<(N_NODES + 63) / 64, 512, 0, stream>>>(
        t, h8b, row_ptr, colu, WlPack, bl, gid, h, h8a, 0,
        Gsum + (size_t)2 * N_GRAPHS * HIDDEN);

    k_out<<<N_GRAPHS, 256, 0, stream>>>(Gsum, gcnt, Wout, bout, out);
}

// Round 17
// 325.843 us; speedup vs baseline: 1.6054x; 1.0312x over previous
//
#include <hip/hip_runtime.h>
#include <hip/hip_fp8.h>

#define N_NODES   50000
#define N_EDGES   1600000
#define N_GRAPHS  512
#define IN_SIZE   44
#define HIDDEN    256
#define CONV_NUMS 3
#define NBK       ((N_NODES + 255) / 256)   // 196 dst-buckets of 256 nodes
#define CAP       16384                     // fixed colu/pairs stride per bucket
#define XK        48                        // bf16 X row stride (self-term)
#define XK8       64                        // fp8 X row stride (gather table, padded)

typedef __attribute__((ext_vector_type(8))) short short8v;            // 8 bf16 = 16 B
typedef __attribute__((ext_vector_type(8))) unsigned short ushort8v;  // 8 u16 = 16 B
typedef __attribute__((ext_vector_type(4))) float f32x4;              // MFMA C/D frag
typedef __attribute__((ext_vector_type(2))) float f32x2;

__device__ __forceinline__ float bf2f(unsigned short u) {
    return __uint_as_float(((unsigned int)u) << 16);
}
__device__ __forceinline__ unsigned short f2bf(float f) {
    unsigned int u = __float_as_uint(f);
    unsigned int r = (u + 0x7fffu + ((u >> 16) & 1u)) >> 16;  // RNE
    return (unsigned short)r;
}

// ---- fp8 e4m3 (OCP on gfx950) helpers: HW cvt with HIP-type fallback ----
#if __has_builtin(__builtin_amdgcn_cvt_f32_fp8)
template <int SEL>
__device__ __forceinline__ float fp8tof(unsigned int w) {
    return __builtin_amdgcn_cvt_f32_fp8((int)w, SEL);
}
#else
template <int SEL>
__device__ __forceinline__ float fp8tof(unsigned int w) {
    __hip_fp8_e4m3 q;
    q.__x = (__hip_fp8_storage_t)((w >> (SEL * 8)) & 0xff);
    return (float)q;
}
#endif

#if __has_builtin(__builtin_amdgcn_cvt_pk_f32_fp8)
template <int HI>
__device__ __forceinline__ f32x2 pk2f(unsigned int w) {
    return __builtin_amdgcn_cvt_pk_f32_fp8((int)w, HI != 0);
}
#else
template <int HI>
__device__ __forceinline__ f32x2 pk2f(unsigned int w) {
    f32x2 r;
    r.x = fp8tof<2 * HI>(w);
    r.y = fp8tof<2 * HI + 1>(w);
    return r;
}
#endif

#if __has_builtin(__builtin_amdgcn_cvt_pk_fp8_f32)
__device__ __forceinline__ unsigned int pk4fp8(float f0, float f1, float f2, float f3) {
    int lo = __builtin_amdgcn_cvt_pk_fp8_f32(f0, f1, 0, false);
    return (unsigned int)__builtin_amdgcn_cvt_pk_fp8_f32(f2, f3, lo, true);
}
#else
__device__ __forceinline__ unsigned int pk4fp8(float f0, float f1, float f2, float f3) {
    __hip_fp8_e4m3 a(f0), b(f1), c(f2), d(f3);
    return (unsigned int)a.__x | ((unsigned int)b.__x << 8) |
           ((unsigned int)c.__x << 16) | ((unsigned int)d.__x << 24);
}
#endif

__device__ __forceinline__ unsigned char f2fp8(float f) {
    return (unsigned char)(pk4fp8(f, 0.f, 0.f, 0.f) & 0xff);
}

// ========= fused: graph histogram + cursor init + weight pack + X cast ======
// blocks [0,64): gcnt histogram (+ block 0 inits bucket_cursor[b]=b*CAP);
// [64,96): WlPack; [96,104): WprojPack; [104, 104+ncast): Xb/Xb8p cast.
__global__ __launch_bounds__(256) void k_build0(const int* __restrict__ gid,
                                                const float* __restrict__ Wl,
                                                const float* __restrict__ Wproj,
                                                const float* __restrict__ X,
                                                int* __restrict__ bucket_cursor,
                                                int* __restrict__ gcnt,
                                                unsigned short* __restrict__ WlPack,
                                                unsigned short* __restrict__ WprojPack,
                                                unsigned short* __restrict__ Xb,
                                                unsigned char* __restrict__ Xb8p) {
    int b = blockIdx.x;
    int tid = threadIdx.x;
    if (b < 64) {
        if (b == 0 && tid < NBK) bucket_cursor[tid] = tid * CAP;
        __shared__ int hg[N_GRAPHS];
        for (int i = tid; i < N_GRAPHS; i += 256) hg[i] = 0;
        __syncthreads();
        int t = b * 256 + tid;
        int stride = 64 * 256;
        for (int v = t; v < N_NODES; v += stride) atomicAdd(&hg[gid[v]], 1);
        __syncthreads();
        for (int i = tid; i < N_GRAPHS; i += 256) if (hg[i]) atomicAdd(&gcnt[i], hg[i]);
    } else if (b < 96) {                // WlPack: 8192 frags
        int i = (b - 64) * 256 + tid;
        int kg = i >> 8, n = i & 255;
        short8v v;
#pragma unroll
        for (int j = 0; j < 8; j++) v[j] = (short)f2bf(Wl[(kg * 8 + j) * HIDDEN + n]);
        *(short8v*)(WlPack + (size_t)(kg * 256 + n) * 8) = v;
    } else if (b < 104) {               // WprojPack: kg in [0,8), zero-pad k>=44
        int i = (b - 96) * 256 + tid;
        int kg = i >> 8, n = i & 255;
        short8v v;
#pragma unroll
        for (int j = 0; j < 8; j++) {
            int k = kg * 8 + j;
            v[j] = (k < IN_SIZE) ? (short)f2bf(Wproj[k * HIDDEN + n]) : (short)0;
        }
        *(short8v*)(WprojPack + (size_t)(kg * 256 + n) * 8) = v;
    } else {                            // Xb8p: N x 64 fp8 (+ Xb: N x 48 bf16)
        const int TOT8 = N_NODES * XK8;
        int id0 = (b - 104) * 2048 + tid;
#pragma unroll
        for (int j = 0; j < 8; j++) {
            int id = id0 + j * 256;
            if (id < TOT8) {
                int row = id >> 6, c = id & 63;
                float val = (c < IN_SIZE) ? X[row * IN_SIZE + c] : 0.f;
                Xb8p[id] = f2fp8(val);
                if (c < XK) Xb[(size_t)row * XK + c] = f2bf(val);
            }
        }
    }
}

// Pass B: LDS-sort 8192-edge chunks by bucket; dst cached in registers across
// both passes; write packed (b,ldst,src) runs into fixed-stride bucket regions.
#define BCH 8192
__global__ __launch_bounds__(256) void k_passB(const int* __restrict__ src,
                                               const int* __restrict__ dst,
                                               int* __restrict__ bucket_cursor,
                                               int* __restrict__ pairs) {
    __shared__ int hist[NBK];
    __shared__ int excl[NBK];
    __shared__ int cur[NBK];
    __shared__ int gbase[NBK];
    __shared__ int lp[BCH];
    __shared__ int sc[256];
    int tid = threadIdx.x;
    int e0 = blockIdx.x * BCH;
    int cnt = min(BCH, N_EDGES - e0);
    for (int i = tid; i < NBK; i += 256) hist[i] = 0;
    __syncthreads();
    int dreg[BCH / 256];                 // 32 edge-dsts per thread
#pragma unroll
    for (int j = 0; j < BCH / 256; j++) {
        int i = tid + j * 256;
        dreg[j] = (i < cnt) ? dst[e0 + i] : -1;
    }
#pragma unroll
    for (int j = 0; j < BCH / 256; j++)
        if (dreg[j] >= 0) atomicAdd(&hist[dreg[j] >> 8], 1);
    __syncthreads();
    int hv = (tid < NBK) ? hist[tid] : 0;
    sc[tid] = hv;
    __syncthreads();
    for (int off = 1; off < 256; off <<= 1) {
        int a = (tid >= off) ? sc[tid - off] : 0;
        __syncthreads();
        sc[tid] += a;
        __syncthreads();
    }
    if (tid < NBK) {
        excl[tid] = sc[tid] - hv;
        cur[tid]  = sc[tid] - hv;
    }
    __syncthreads();
#pragma unroll
    for (int j = 0; j < BCH / 256; j++) {
        int d = dreg[j];
        if (d >= 0) {
            int b = d >> 8;
            int pos = atomicAdd(&cur[b], 1);
            lp[pos] = (b << 24) | ((d & 255) << 16) | src[e0 + tid + j * 256];
        }
    }
    __syncthreads();
    if (tid < NBK && hist[tid] > 0)
        gbase[tid] = atomicAdd(&bucket_cursor[tid], hist[tid]);
    __syncthreads();
    for (int i = tid; i < cnt; i += 256) {
        int p = lp[i];
        int b = (p >> 24) & 0xff;
        pairs[gbase[b] + (i - excl[b])] = p;
    }
}

// Pass C: one block per bucket -> packed row_ptr (start | deg<<24) + colu.
// Row starts padded to multiples of 8 entries (16 B-aligned ushort8 loads).
__global__ __launch_bounds__(256) void k_passC(const int* __restrict__ pairs,
                                               const int* __restrict__ bucket_cursor,
                                               int* __restrict__ row_ptr,
                                               unsigned short* __restrict__ colu) {
    __shared__ int hist[256];
    __shared__ int cur[256];
    __shared__ int sc[256];
    int b = blockIdx.x;
    int tid = threadIdx.x;
    int v0 = b << 8;
    int e0 = b * CAP;
    int e1 = bucket_cursor[b];          // base + count after passB
    hist[tid] = 0;
    __syncthreads();
    for (int i = e0 + tid; i < e1; i += 256) atomicAdd(&hist[(pairs[i] >> 16) & 0xff], 1);
    __syncthreads();
    int hv = hist[tid];
    int hv8 = (hv + 7) & ~7;            // 8-aligned row span
    sc[tid] = hv8;
    __syncthreads();
    for (int off = 1; off < 256; off <<= 1) {
        int a = (tid >= off) ? sc[tid - off] : 0;
        __syncthreads();
        sc[tid] += a;
        __syncthreads();
    }
    int base = e0 + sc[tid] - hv8;
    int v = v0 + tid;
    if (v < N_NODES) row_ptr[v] = base | (hv << 24);
    cur[tid] = base;
    __syncthreads();
    for (int i = e0 + tid; i < e1; i += 256) {
        int p = pairs[i];
        int pos = atomicAdd(&cur[(p >> 16) & 0xff], 1);
        colu[pos] = (unsigned short)(p & 0xffff);
    }
}

// ====== fused layer 1: 4-edge-batched fp8-X gather -> 2x MFMA -> store ======
#define TLS 264
#define K1S 72
__global__ __launch_bounds__(512, 8) void k_layer1(const unsigned short* __restrict__ Xb,
                                                   const unsigned char* __restrict__ Xb8p,
                                                   const int* __restrict__ row_ptr,
                                                   const unsigned short* __restrict__ colu,
                                                   const unsigned short* __restrict__ WprojPack,
                                                   const float* __restrict__ bp,
                                                   const unsigned short* __restrict__ WlPack,
                                                   const float* __restrict__ bl,
                                                   const int* __restrict__ gid,
                                                   unsigned short* __restrict__ hout,
                                                   unsigned char* __restrict__ hout8,
                                                   float* __restrict__ GsumL) {
    __shared__ unsigned short tl[64 * TLS];
    unsigned short* tl1 = tl;          // overlay: 64*K1S = 4608 shorts
    float* redbase = (float*)(tl + 64 * K1S);   // dead zone of tl in phase 1
    __shared__ float bpm[64];
    __shared__ int gl[64];
    int tid = threadIdx.x;
    int w = tid >> 6, lane = tid & 63, quad = lane >> 4, l16 = lane & 15;
    int g = lane >> 4, sub = lane & 15;
    int m0 = blockIdx.x * 64;
    float* red = redbase + w * 256;

    // ---- phase 1: batched fp8 gather of X rows (4 edges/load, 4 in flight) --
    const unsigned int* X8 = (const unsigned int*)Xb8p;   // row stride 16 uints
    for (int rr = 0; rr < 8; rr++) {
        int r = w * 8 + rr;
        int v = m0 + r;
        f32x2 A = {0.f, 0.f};
        f32x2 Bv = {0.f, 0.f};
        int s = 0, e = 0;
        if (v < N_NODES) {
            int rp = row_ptr[v];
            s = rp & 0xffffff;
            e = s + (int)(((unsigned int)rp) >> 24);
        }
        int i = s;
        for (; i + 16 <= e; i += 16) {
            int ua = colu[i + g];
            int ub = colu[i + 4 + g];
            int uc = colu[i + 8 + g];
            int ud = colu[i + 12 + g];
            unsigned int pa = X8[ua * 16 + sub];
            unsigned int pb = X8[ub * 16 + sub];
            unsigned int pc = X8[uc * 16 + sub];
            unsigned int pd = X8[ud * 16 + sub];
            A  += (pk2f<0>(pa) + pk2f<0>(pb)) + (pk2f<0>(pc) + pk2f<0>(pd));
            Bv += (pk2f<1>(pa) + pk2f<1>(pb)) + (pk2f<1>(pc) + pk2f<1>(pd));
        }
        if (i + 8 <= e) {
            int ua = colu[i + g];
            int ub = colu[i + 4 + g];
            unsigned int pa = X8[ua * 16 + sub];
            unsigned int pb = X8[ub * 16 + sub];
            A  += pk2f<0>(pa) + pk2f<0>(pb);
            Bv += pk2f<1>(pa) + pk2f<1>(pb);
            i += 8;
        }
        if (i + 4 <= e) {
            int ua = colu[i + g];
            unsigned int pa = X8[ua * 16 + sub];
            A += pk2f<0>(pa);
            Bv += pk2f<1>(pa);
            i += 4;
        }
        if (i < e) {   // wave-uniform guard; branchless per-lane tail
            int idx = i + g;
            int cl = (idx < e) ? idx : (e - 1);
            int ua = colu[cl];
            unsigned int pa = X8[ua * 16 + sub];
            float mvalid = (idx < e) ? 1.f : 0.f;
            f32x2 za = pk2f<0>(pa), zb = pk2f<1>(pa);
            A.x += mvalid * za.x; A.y += mvalid * za.y;
            Bv.x += mvalid * zb.x; Bv.y += mvalid * zb.y;
        }
        *(f32x4*)(red + g * 64 + sub * 4) = (f32x4){A.x, A.y, Bv.x, Bv.y};
        float ssum = (red[0 * 64 + lane] + red[1 * 64 + lane])
                   + (red[2 * 64 + lane] + red[3 * 64 + lane]);
        float val = 0.f;
        float mul = 1.f;
        if (v < N_NODES) {
            float inv = 0.f;
            if (e > s) { inv = 1.0f / (float)(e - s); mul = 2.f; }
            float self = (lane < XK) ? bf2f(Xb[(size_t)v * XK + lane]) : 0.f;
            val = self + inv * ssum;
        }
        tl1[r * K1S + lane] = (lane < XK) ? f2bf(val) : (unsigned short)0;
        if (lane == 0) bpm[r] = mul;
    }
    if (tid < 64) gl[tid] = (m0 + tid < N_NODES) ? gid[m0 + tid] : -1;
    __syncthreads();

    // ---- phase 2: MFMA stage 1 (A = tl1 64x64, B = WprojPack) ----
    int n0 = w * 32;
    f32x4 acc[4][2];
#pragma unroll
    for (int mt = 0; mt < 4; mt++) {
        acc[mt][0] = (f32x4){0.f, 0.f, 0.f, 0.f};
        acc[mt][1] = (f32x4){0.f, 0.f, 0.f, 0.f};
    }
#pragma unroll
    for (int ks = 0; ks < 2; ks++) {
        int kg = ks * 4 + quad;
        short8v bfr0 = *(const short8v*)(WprojPack + (size_t)(kg * 256 + n0 + l16) * 8);
        short8v bfr1 = *(const short8v*)(WprojPack + (size_t)(kg * 256 + n0 + 16 + l16) * 8);
#pragma unroll
        for (int mt = 0; mt < 4; mt++) {
            short8v afr = *(const short8v*)(tl1 + (mt * 16 + l16) * K1S + ks * 32 + quad * 8);
            acc[mt][0] = __builtin_amdgcn_mfma_f32_16x16x32_bf16(afr, bfr0, acc[mt][0], 0, 0, 0);
            acc[mt][1] = __builtin_amdgcn_mfma_f32_16x16x32_bf16(afr, bfr1, acc[mt][1], 0, 0, 0);
        }
    }
    __syncthreads();   // all tl1 reads complete before tl writes (overlay!)
#pragma unroll
    for (int nt = 0; nt < 2; nt++) {
        int colg = n0 + nt * 16 + l16;
        float bb = bp[colg];
#pragma unroll
        for (int mt = 0; mt < 4; mt++)
#pragma unroll
            for (int r = 0; r < 4; r++) {
                int row = mt * 16 + quad * 4 + r;
                tl[row * TLS + colg] = f2bf(acc[mt][nt][r] + bb * bpm[row]);
            }
    }
    __syncthreads();

    // ---- phase 3: MFMA stage 2 (A = tl 64x256, B = WlPack) ----
#pragma unroll
    for (int mt = 0; mt < 4; mt++) {
        acc[mt][0] = (f32x4){0.f, 0.f, 0.f, 0.f};
        acc[mt][1] = (f32x4){0.f, 0.f, 0.f, 0.f};
    }
#pragma unroll
    for (int ks = 0; ks < 8; ks++) {
        int kg = ks * 4 + quad;
        short8v bfr0 = *(const short8v*)(WlPack + (size_t)(kg * 256 + n0 + l16) * 8);
        short8v bfr1 = *(const short8v*)(WlPack + (size_t)(kg * 256 + n0 + 16 + l16) * 8);
#pragma unroll
        for (int mt = 0; mt < 4; mt++) {
            short8v afr = *(const short8v*)(tl + (mt * 16 + l16) * TLS + ks * 32 + quad * 8);
            acc[mt][0] = __builtin_amdgcn_mfma_f32_16x16x32_bf16(afr, bfr0, acc[mt][0], 0, 0, 0);
            acc[mt][1] = __builtin_amdgcn_mfma_f32_16x16x32_bf16(afr, bfr1, acc[mt][1], 0, 0, 0);
        }
    }
    __syncthreads();

    // ---- phase 4: epilogue ----
#pragma unroll
    for (int nt = 0; nt < 2; nt++) {
        int colg = n0 + nt * 16 + l16;
        float bb = bl[colg];
#pragma unroll
        for (int mt = 0; mt < 4; mt++)
#pragma unroll
            for (int r = 0; r < 4; r++)
                tl[(mt * 16 + quad * 4 + r) * TLS + colg] = f2bf(acc[mt][nt][r] + bb);
    }
    __syncthreads();

    // ---- phase 5a: coalesced stores (bf16 + fp8 mirror) ----
    for (int i = tid; i < 64 * 64; i += 512) {
        int r = i >> 6, c4 = i & 63;
        int v = m0 + r;
        if (v < N_NODES) {
            ushort4 q = *(ushort4*)(tl + r * TLS + c4 * 4);
            ((ushort4*)hout)[(size_t)v * 64 + c4] = q;
            ((unsigned int*)hout8)[(size_t)v * 64 + c4] =
                pk4fp8(bf2f(q.x), bf2f(q.y), bf2f(q.z), bf2f(q.w));
        }
    }
    // ---- phase 5b: fused readout ----
    {
        int c = tid & 255;
        int r0 = (tid >> 8) * 32;
        float a2 = 0.f;
        int curg = gl[r0];
        for (int r = r0; r < r0 + 32; r++) {
            int gg = gl[r];
            if (gg < 0) break;
            if (gg != curg) {
                atomicAdd(&GsumL[curg * HIDDEN + c], a2);
                a2 = 0.f;
                curg = gg;
            }
            a2 += bf2f(tl[r * TLS + c]);
        }
        if (curg >= 0) atomicAdd(&GsumL[curg * HIDDEN + c], a2);
    }
}

// ====== fused layer (2,3): fp8 gather (16 loads in flight) -> MFMA ==========
__global__ __launch_bounds__(512, 8) void k_layer(const unsigned short* __restrict__ h,
                                                  const unsigned char* __restrict__ h8,
                                                  const int* __restrict__ row_ptr,
                                                  const unsigned short* __restrict__ colu,
                                                  const unsigned short* __restrict__ Wpack,
                                                  const float* __restrict__ bias,
                                                  const int* __restrict__ gid,
                                                  unsigned short* __restrict__ hout,
                                                  unsigned char* __restrict__ hout8,
                                                  int wflags,   // bit0: hout, bit1: hout8
                                                  float* __restrict__ GsumL) {
    __shared__ unsigned short tl[64 * TLS];   // 33792 B
    __shared__ int gl[64];
    int tid = threadIdx.x;
    int w = tid >> 6, lane = tid & 63, quad = lane >> 4, l16 = lane & 15;
    int m0 = blockIdx.x * 64;

    // ---- phase 1: fp8 gather + mean; 16 loads in flight; 16B colu loads ----
    const unsigned int* h8v = (const unsigned int*)h8;   // 4 fp8 per lane (4 B)
    const ushort4* hv = (const ushort4*)h;
    for (int rr = 0; rr < 8; rr++) {
        int r = w * 8 + rr;
        int v = m0 + r;
        f32x2 A = {0.f, 0.f};   // cols lane*4 + {0,1}
        f32x2 B = {0.f, 0.f};   // cols lane*4 + {2,3}
        if (v < N_NODES) {
            int rp = row_ptr[v];
            int s = rp & 0xffffff;
            int e = s + (int)(((unsigned int)rp) >> 24);
            int i = s;
            for (; i + 16 <= e; i += 16) {
                ushort8v ca = *(const ushort8v*)(colu + i);       // 16B aligned
                ushort8v cb = *(const ushort8v*)(colu + i + 8);
                unsigned int p0 = h8v[(size_t)ca[0] * 64 + lane];
                unsigned int p1 = h8v[(size_t)ca[1] * 64 + lane];
                unsigned int p2 = h8v[(size_t)ca[2] * 64 + lane];
                unsigned int p3 = h8v[(size_t)ca[3] * 64 + lane];
                unsigned int p4 = h8v[(size_t)ca[4] * 64 + lane];
                unsigned int p5 = h8v[(size_t)ca[5] * 64 + lane];
                unsigned int p6 = h8v[(size_t)ca[6] * 64 + lane];
                unsigned int p7 = h8v[(size_t)ca[7] * 64 + lane];
                unsigned int q0 = h8v[(size_t)cb[0] * 64 + lane];
                unsigned int q1 = h8v[(size_t)cb[1] * 64 + lane];
                unsigned int q2 = h8v[(size_t)cb[2] * 64 + lane];
                unsigned int q3 = h8v[(size_t)cb[3] * 64 + lane];
                unsigned int q4 = h8v[(size_t)cb[4] * 64 + lane];
                unsigned int q5 = h8v[(size_t)cb[5] * 64 + lane];
                unsigned int q6 = h8v[(size_t)cb[6] * 64 + lane];
                unsigned int q7 = h8v[(size_t)cb[7] * 64 + lane];
                A += ((pk2f<0>(p0) + pk2f<0>(p1)) + (pk2f<0>(p2) + pk2f<0>(p3)))
                   + ((pk2f<0>(p4) + pk2f<0>(p5)) + (pk2f<0>(p6) + pk2f<0>(p7)))
                   + ((pk2f<0>(q0) + pk2f<0>(q1)) + (pk2f<0>(q2) + pk2f<0>(q3)))
                   + ((pk2f<0>(q4) + pk2f<0>(q5)) + (pk2f<0>(q6) + pk2f<0>(q7)));
                B += ((pk2f<1>(p0) + pk2f<1>(p1)) + (pk2f<1>(p2) + pk2f<1>(p3)))
                   + ((pk2f<1>(p4) + pk2f<1>(p5)) + (pk2f<1>(p6) + pk2f<1>(p7)))
                   + ((pk2f<1>(q0) + pk2f<1>(q1)) + (pk2f<1>(q2) + pk2f<1>(q3)))
                   + ((pk2f<1>(q4) + pk2f<1>(q5)) + (pk2f<1>(q6) + pk2f<1>(q7)));
            }
            if (i + 8 <= e) {
                ushort8v cv = *(const ushort8v*)(colu + i);
                unsigned int p0 = h8v[(size_t)cv[0] * 64 + lane];
                unsigned int p1 = h8v[(size_t)cv[1] * 64 + lane];
                unsigned int p2 = h8v[(size_t)cv[2] * 64 + lane];
                unsigned int p3 = h8v[(size_t)cv[3] * 64 + lane];
                unsigned int p4 = h8v[(size_t)cv[4] * 64 + lane];
                unsigned int p5 = h8v[(size_t)cv[5] * 64 + lane];
                unsigned int p6 = h8v[(size_t)cv[6] * 64 + lane];
                unsigned int p7 = h8v[(size_t)cv[7] * 64 + lane];
                A += (pk2f<0>(p0) + pk2f<0>(p1)) + (pk2f<0>(p2) + pk2f<0>(p3))
                   + (pk2f<0>(p4) + pk2f<0>(p5)) + (pk2f<0>(p6) + pk2f<0>(p7));
                B += (pk2f<1>(p0) + pk2f<1>(p1)) + (pk2f<1>(p2) + pk2f<1>(p3))
                   + (pk2f<1>(p4) + pk2f<1>(p5)) + (pk2f<1>(p6) + pk2f<1>(p7));
                i += 8;
            }
            if (i + 4 <= e) {
                ushort4 cv = *(const ushort4*)(colu + i);     // 8B aligned
                unsigned int p0 = h8v[(size_t)cv.x * 64 + lane];
                unsigned int p1 = h8v[(size_t)cv.y * 64 + lane];
                unsigned int p2 = h8v[(size_t)cv.z * 64 + lane];
                unsigned int p3 = h8v[(size_t)cv.w * 64 + lane];
                A += (pk2f<0>(p0) + pk2f<0>(p1)) + (pk2f<0>(p2) + pk2f<0>(p3));
                B += (pk2f<1>(p0) + pk2f<1>(p1)) + (pk2f<1>(p2) + pk2f<1>(p3));
                i += 4;
            }
            for (; i < e; i++) {
                unsigned int p = h8v[(size_t)colu[i] * 64 + lane];
                A += pk2f<0>(p);
                B += pk2f<1>(p);
            }
            float inv = (e > s) ? 1.0f / (float)(e - s) : 0.0f;
            ushort4 hs = hv[(size_t)v * 64 + lane];   // self-term bf16
            A.x = bf2f(hs.x) + inv * A.x;
            A.y = bf2f(hs.y) + inv * A.y;
            B.x = bf2f(hs.z) + inv * B.x;
            B.y = bf2f(hs.w) + inv * B.y;
        }
        ushort4 o;
        o.x = f2bf(A.x); o.y = f2bf(A.y); o.z = f2bf(B.x); o.w = f2bf(B.y);
        *(ushort4*)(tl + r * TLS + lane * 4) = o;
    }
    if (tid < 64) gl[tid] = (m0 + tid < N_NODES) ? gid[m0 + tid] : -1;
    __syncthreads();

    // ---- phase 2: MFMA ----
    int n0 = w * 32;
    f32x4 acc[4][2];
#pragma unroll
    for (int mt = 0; mt < 4; mt++) {
        acc[mt][0] = (f32x4){0.f, 0.f, 0.f, 0.f};
        acc[mt][1] = (f32x4){0.f, 0.f, 0.f, 0.f};
    }
#pragma unroll
    for (int ks = 0; ks < 8; ks++) {
        int kg = ks * 4 + quad;
        short8v bfr0 = *(const short8v*)(Wpack + (size_t)(kg * 256 + n0 + l16) * 8);
        short8v bfr1 = *(const short8v*)(Wpack + (size_t)(kg * 256 + n0 + 16 + l16) * 8);
#pragma unroll
        for (int mt = 0; mt < 4; mt++) {
            short8v afr = *(const short8v*)(tl + (mt * 16 + l16) * TLS + ks * 32 + quad * 8);
            acc[mt][0] = __builtin_amdgcn_mfma_f32_16x16x32_bf16(afr, bfr0, acc[mt][0], 0, 0, 0);
            acc[mt][1] = __builtin_amdgcn_mfma_f32_16x16x32_bf16(afr, bfr1, acc[mt][1], 0, 0, 0);
        }
    }
    __syncthreads();

    // ---- phase 3: epilogue ----
#pragma unroll
    for (int nt = 0; nt < 2; nt++) {
        int colg = n0 + nt * 16 + l16;
        float bb = bias[colg];
#pragma unroll
        for (int mt = 0; mt < 4; mt++)
#pragma unroll
            for (int r = 0; r < 4; r++)
                tl[(mt * 16 + quad * 4 + r) * TLS + colg] = f2bf(acc[mt][nt][r] + bb);
    }
    __syncthreads();

    // ---- phase 4a: coalesced stores (flag-gated) ----
    if (wflags) {
        for (int i = tid; i < 64 * 64; i += 512) {
            int r = i >> 6, c4 = i & 63;
            int v = m0 + r;
            if (v < N_NODES) {
                ushort4 q = *(ushort4*)(tl + r * TLS + c4 * 4);
                if (wflags & 1)
                    ((ushort4*)hout)[(size_t)v * 64 + c4] = q;
                if (wflags & 2)
                    ((unsigned int*)hout8)[(size_t)v * 64 + c4] =
                        pk4fp8(bf2f(q.x), bf2f(q.y), bf2f(q.z), bf2f(q.w));
            }
        }
    }
    // ---- phase 4b: fused readout ----
    {
        int c = tid & 255;
        int r0 = (tid >> 8) * 32;
        float a2 = 0.f;
        int curg = gl[r0];
        for (int r = r0; r < r0 + 32; r++) {
            int g = gl[r];
            if (g < 0) break;
            if (g != curg) {
                atomicAdd(&GsumL[curg * HIDDEN + c], a2);
                a2 = 0.f;
                curg = g;
            }
            a2 += bf2f(tl[r * TLS + c]);
        }
        if (curg >= 0) atomicAdd(&GsumL[curg * HIDDEN + c], a2);
    }
}

// ================= out[g] = (concat gmean) @ W_out + b_out ==================
__global__ __launch_bounds__(256) void k_out(const float* __restrict__ Gsum,
                                             const int* __restrict__ gcnt,
                                             const float* __restrict__ Wout,
                                             const float* __restrict__ bout,
                                             float* __restrict__ out) {
    int g = blockIdx.x;
    int c = threadIdx.x;
    __shared__ float gm[HIDDEN * CONV_NUMS];
    float invc = 1.0f / fmaxf((float)gcnt[g], 1.0f);
    for (int i = c; i < HIDDEN * CONV_NUMS; i += 256) {
        int l = i >> 8;
        int k = i & 255;
        gm[i] = Gsum[(size_t)l * N_GRAPHS * HIDDEN + g * HIDDEN + k] * invc;
    }
    __syncthreads();
    float acc = bout[c];
    const float4* gm4 = (const float4*)gm;
    for (int k0 = 0; k0 < HIDDEN * CONV_NUMS; k0 += 4) {
        float4 gv = gm4[k0 >> 2];
        acc += gv.x * Wout[(k0 + 0) * HIDDEN + c];
        acc += gv.y * Wout[(k0 + 1) * HIDDEN + c];
        acc += gv.z * Wout[(k0 + 2) * HIDDEN + c];
        acc += gv.w * Wout[(k0 + 3) * HIDDEN + c];
    }
    out[g * HIDDEN + c] = acc;
}

extern "C" void kernel_launch(void* const* d_in, const int* in_sizes, int n_in,
                              void* d_out, int out_size, void* d_ws, size_t ws_size,
                              hipStream_t stream) {
    const float* X    = (const float*)d_in[0];
    const int*   src  = (const int*)d_in[1];
    const int*   dst  = (const int*)d_in[2];
    const int*   gid  = (const int*)d_in[3];
    const float* Wp   = (const float*)d_in[4];
    const float* bp   = (const float*)d_in[5];
    const float* Wl   = (const float*)d_in[6];
    const float* bl   = (const float*)d_in[7];
    const float* Wout = (const float*)d_in[8];
    const float* bout = (const float*)d_in[9];
    float* out = (float*)d_out;

    char* ws = (char*)d_ws;
    size_t off = 0;
    auto alloc = [&](size_t bytes) {
        char* p = ws + off;
        off += (bytes + 255) & ~size_t(255);
        return p;
    };
    unsigned short* h         = (unsigned short*)alloc(sizeof(short) * N_NODES * HIDDEN);
    unsigned short* t         = (unsigned short*)alloc(sizeof(short) * N_NODES * HIDDEN);
    unsigned char*  h8a       = (unsigned char*)alloc((size_t)N_NODES * HIDDEN);
    unsigned char*  h8b       = (unsigned char*)alloc((size_t)N_NODES * HIDDEN);
    unsigned short* WlPack    = (unsigned short*)alloc(sizeof(short) * HIDDEN * HIDDEN);
    unsigned short* WprojPack = (unsigned short*)alloc(sizeof(short) * 8 * 256 * 8);
    unsigned short* Xb        = (unsigned short*)alloc(sizeof(short) * N_NODES * XK);
    unsigned char*  Xb8p      = (unsigned char*)alloc((size_t)N_NODES * XK8);
    int*   pairs   = (int*)alloc(sizeof(int) * NBK * CAP);
    unsigned short* colu = (unsigned short*)alloc(sizeof(short) * NBK * CAP);
    int*   row_ptr = (int*)alloc(sizeof(int) * (N_NODES + 1));
    int*   bucket_cursor = (int*)alloc(sizeof(int) * NBK);
    // contiguous zero region: gcnt | Gsum -> one memset
    char*  zero0 = ws + off;
    int*   gcnt = (int*)alloc(sizeof(int) * N_GRAPHS);
    float* Gsum = (float*)alloc(sizeof(float) * CONV_NUMS * N_GRAPHS * HIDDEN);
    size_t zero_bytes = (size_t)((char*)(Gsum + CONV_NUMS * N_GRAPHS * HIDDEN) - zero0);

    hipMemsetAsync(zero0, 0, zero_bytes, stream);

    {
        const int TOT8 = N_NODES * XK8;
        int ncast = (TOT8 + 2047) / 2048;
        k_build0<<<104 + ncast, 256, 0, stream>>>(gid, Wl, Wp, X, bucket_cursor,
                                                  gcnt, WlPack, WprojPack, Xb, Xb8p);
    }
    k_passB<<<(N_EDGES + BCH - 1) / BCH, 256, 0, stream>>>(src, dst, bucket_cursor, pairs);
    k_passC<<<NBK, 256, 0, stream>>>(pairs, bucket_cursor, row_ptr, colu);

    // layer 1 (fused proj + conv1 + readout); writes bf16 h + fp8 mirror h8a
    k_layer1<<<(N_NODES + 63) / 64, 512, 0, stream>>>(
        Xb, Xb8p, row_ptr, colu, WprojPack, bp, WlPack, bl, gid, h, h8a, Gsum);

    // layer 2: gather fp8(h8a), self bf16 h -> t + h8b
    k_layer<<<(N_NODES + 63) / 64, 512, 0, stream>>>(
        h, h8a, row_ptr, colu, WlPack, bl, gid, t, h8b, 3,
        Gsum + (size_t)1 * N_GRAPHS * HIDDEN);

    // layer 3: gather fp8(h8b), self bf16 t -> readout only (no stores)
    k_layer<<<(N_NODES + 63) / 64, 512, 0, stream>>>(
        t, h8b, row_ptr, colu, WlPack, bl, gid, h, h8a, 0,
        Gsum + (size_t)2 * N_GRAPHS * HIDDEN);

    k_out<<<N_GRAPHS, 256, 0, stream>>>(Gsum, gcnt, Wout, bout, out);
}